// Round 2
// baseline (196.542 us; speedup 1.0000x reference)
//
#include <hip/hip_runtime.h>
#include <hip/hip_bf16.h>

#define NUM_C 1000
#define DIM   128
#define MM    64
#define BB    64
#define LL    512
#define NROWS (BB * LL)   // 32768

typedef unsigned short u16;
typedef unsigned int   u32;
typedef short bfrag __attribute__((ext_vector_type(8)));   // 8 bf16 (4 VGPRs)
typedef float f32x4 __attribute__((ext_vector_type(4)));   // MFMA acc

__device__ __forceinline__ float sigmoidf_fast(float x) { return 1.f / (1.f + __expf(-x)); }
__device__ __forceinline__ float tanhf_fast(float x) { return 1.f - 2.f / (__expf(2.f * x) + 1.f); }

__device__ __forceinline__ u16 f2bf(float x) {            // RNE f32->bf16 bits
    u32 u = __float_as_uint(x);
    return (u16)((u + 0x7FFFu + ((u >> 16) & 1u)) >> 16);
}
__device__ __forceinline__ float bf2f(u16 h) { return __uint_as_float(((u32)h) << 16); }

// DPP quad_perm swaps + row rotates (VALU-only, verified rounds 5-14)
__device__ __forceinline__ float quad_swap1(float x) {
    return __int_as_float(__builtin_amdgcn_mov_dpp(__float_as_int(x), 0xB1, 0xF, 0xF, true));
}
__device__ __forceinline__ float quad_swap2(float x) {
    return __int_as_float(__builtin_amdgcn_mov_dpp(__float_as_int(x), 0x4E, 0xF, 0xF, true));
}
__device__ __forceinline__ float row_ror4(float x) {
    return __int_as_float(__builtin_amdgcn_mov_dpp(__float_as_int(x), 0x124, 0xF, 0xF, true));
}
__device__ __forceinline__ float row_ror8(float x) {
    return __int_as_float(__builtin_amdgcn_mov_dpp(__float_as_int(x), 0x128, 0xF, 0xF, true));
}

// ---------------------------------------------------------------------------
// Prep: B-side weights as bf16 hi/lo ([n][k] transposed); A-side embeddings
// Ek/Ev pre-converted to bf16 hi ONCE (removes per-row conversion in kAB/kD).
// ---------------------------------------------------------------------------
__global__ __launch_bounds__(256) void kP(const float* __restrict__ We,
                                          const float* __restrict__ Wa,
                                          const float* __restrict__ Wf,
                                          const float* __restrict__ Mk,
                                          const float* __restrict__ Ek,
                                          const float* __restrict__ Ev,
                                          u16* weT_hi, u16* weT_lo,
                                          u16* waT_hi, u16* waT_lo,
                                          u16* wfT_hi, u16* wfT_lo,
                                          u16* mkT_hi, u16* mkT_lo,
                                          u16* ekbf, u16* evbf) {
    int idx = blockIdx.x * 256 + threadIdx.x;   // 0..32767
    if (idx < 128 * 128) {
        int n = idx >> 7, k = idx & 127;
        float we = We[k * DIM + n];
        u16 h = f2bf(we);
        weT_hi[idx] = h; weT_lo[idx] = f2bf(we - bf2f(h));
        float wa = Wa[k * DIM + n];
        u16 h2 = f2bf(wa);
        waT_hi[idx] = h2; waT_lo[idx] = f2bf(wa - bf2f(h2));
    }
    if (idx < 64 * 128) {
        float mk = Mk[idx];
        u16 h = f2bf(mk);
        mkT_hi[idx] = h; mkT_lo[idx] = f2bf(mk - bf2f(h));
    }
    {
        int n = idx >> 8, k = idx & 255;
        float wf = Wf[k * DIM + n];
        u16 h = f2bf(wf);
        wfT_hi[idx] = h; wfT_lo[idx] = f2bf(wf - bf2f(h));
    }
    for (int i = idx; i < NUM_C * DIM; i += 32768) ekbf[i] = f2bf(Ek[i]);
    for (int i = idx; i < 2 * NUM_C * DIM; i += 32768) evbf[i] = f2bf(Ev[i]);
}

// ---------------------------------------------------------------------------
// Fused kAB (MFMA, A=bf16-hi only, B=hi+lo). Blocks [0,512): kA role.
// Blocks [512,1024): kB role. 64 rows/block; staging = pure u16 gather.
// ---------------------------------------------------------------------------
__global__ __launch_bounds__(256) void kAB(const int* __restrict__ q,
                                           const int* __restrict__ r,
                                           const u16* __restrict__ ekbf,
                                           const u16* __restrict__ evbf,
                                           const u16* __restrict__ mkT_hi, const u16* __restrict__ mkT_lo,
                                           const u16* __restrict__ weT_hi, const u16* __restrict__ weT_lo,
                                           const u16* __restrict__ waT_hi, const u16* __restrict__ waT_lo,
                                           const float* __restrict__ be, const float* __restrict__ ba,
                                           float* __restrict__ w_out,
                                           float2* __restrict__ ea_out) {
    __shared__ __align__(16) u16 shi[4][16][136];
    __shared__ float slab[4][64];
    const int tid = threadIdx.x;
    const int lane = tid & 63;
    const int wv = tid >> 6;
    const int nloc = lane & 15;
    const int quad = lane >> 4;

    if (blockIdx.x < 512) {
        // ---------------- kA role ----------------
        const int base = blockIdx.x * 64;
        {   // stage k = ekbf[q] (already bf16)
            const int row_l = tid >> 2;
            const int rts = row_l >> 4, ms = row_l & 15;
            const int d0 = (tid & 3) * 32;
            const u16* src = ekbf + (size_t)q[base + row_l] * DIM + d0;
            #pragma unroll
            for (int c8 = 0; c8 < 4; ++c8)
                *reinterpret_cast<bfrag*>(&shi[rts][ms][d0 + c8 * 8]) =
                    *reinterpret_cast<const bfrag*>(src + c8 * 8);
        }
        __syncthreads();

        const int n = wv * 16 + nloc;      // m index
        bfrag Bh[4], Bl[4];
        #pragma unroll
        for (int kc = 0; kc < 4; ++kc) {
            const int ko = kc * 32 + quad * 8;
            Bh[kc] = *reinterpret_cast<const bfrag*>(mkT_hi + n * DIM + ko);
            Bl[kc] = *reinterpret_cast<const bfrag*>(mkT_lo + n * DIM + ko);
        }

        f32x4 acc[4];
        #pragma unroll
        for (int t = 0; t < 4; ++t) acc[t] = 0.f;

        #pragma unroll
        for (int rt = 0; rt < 4; ++rt) {
            #pragma unroll
            for (int kc = 0; kc < 4; ++kc) {
                const int ko = kc * 32 + quad * 8;
                bfrag Ah = *reinterpret_cast<const bfrag*>(&shi[rt][nloc][ko]);
                acc[rt] = __builtin_amdgcn_mfma_f32_16x16x32_bf16(Ah, Bh[kc], acc[rt], 0, 0, 0);
                acc[rt] = __builtin_amdgcn_mfma_f32_16x16x32_bf16(Ah, Bl[kc], acc[rt], 0, 0, 0);
            }
        }

        float ex[4][4];
        #pragma unroll
        for (int rt = 0; rt < 4; ++rt) {
            #pragma unroll
            for (int rg = 0; rg < 4; ++rg) {
                float e = __expf(acc[rt][rg]);
                ex[rt][rg] = e;
                float s = e;
                s += __shfl_xor(s, 1);
                s += __shfl_xor(s, 2);
                s += __shfl_xor(s, 4);
                s += __shfl_xor(s, 8);
                if (nloc == 0) slab[wv][rt * 16 + quad * 4 + rg] = s;
            }
        }
        __syncthreads();

        #pragma unroll
        for (int rt = 0; rt < 4; ++rt) {
            #pragma unroll
            for (int rg = 0; rg < 4; ++rg) {
                const int row = rt * 16 + quad * 4 + rg;
                float tot = slab[0][row] + slab[1][row] + slab[2][row] + slab[3][row];
                w_out[(size_t)(base + row) * MM + n] = ex[rt][rg] / tot;
            }
        }
    } else {
        // ---------------- kB role ----------------
        const int base = (blockIdx.x - 512) * 64;
        {   // stage v = evbf[x] (already bf16)
            const int row_l = tid >> 2;
            const int rts = row_l >> 4, ms = row_l & 15;
            const int d0 = (tid & 3) * 32;
            const int row = base + row_l;
            const int x = q[row] + NUM_C * r[row];
            const u16* src = evbf + (size_t)x * DIM + d0;
            #pragma unroll
            for (int c8 = 0; c8 < 4; ++c8)
                *reinterpret_cast<bfrag*>(&shi[rts][ms][d0 + c8 * 8]) =
                    *reinterpret_cast<const bfrag*>(src + c8 * 8);
        }
        __syncthreads();

        #pragma unroll
        for (int dt = 0; dt < 2; ++dt) {
            const int n = (wv * 2 + dt) * 16 + nloc;
            bfrag Beh[4], Bel[4], Bah[4], Bal[4];
            #pragma unroll
            for (int kc = 0; kc < 4; ++kc) {
                const int ko = kc * 32 + quad * 8;
                Beh[kc] = *reinterpret_cast<const bfrag*>(weT_hi + n * DIM + ko);
                Bel[kc] = *reinterpret_cast<const bfrag*>(weT_lo + n * DIM + ko);
                Bah[kc] = *reinterpret_cast<const bfrag*>(waT_hi + n * DIM + ko);
                Bal[kc] = *reinterpret_cast<const bfrag*>(waT_lo + n * DIM + ko);
            }
            f32x4 acc_e[4], acc_a[4];
            #pragma unroll
            for (int t = 0; t < 4; ++t) { acc_e[t] = 0.f; acc_a[t] = 0.f; }

            #pragma unroll
            for (int rt = 0; rt < 4; ++rt) {
                #pragma unroll
                for (int kc = 0; kc < 4; ++kc) {
                    const int ko = kc * 32 + quad * 8;
                    bfrag Ah = *reinterpret_cast<const bfrag*>(&shi[rt][nloc][ko]);
                    acc_e[rt] = __builtin_amdgcn_mfma_f32_16x16x32_bf16(Ah, Beh[kc], acc_e[rt], 0, 0, 0);
                    acc_a[rt] = __builtin_amdgcn_mfma_f32_16x16x32_bf16(Ah, Bah[kc], acc_a[rt], 0, 0, 0);
                    acc_e[rt] = __builtin_amdgcn_mfma_f32_16x16x32_bf16(Ah, Bel[kc], acc_e[rt], 0, 0, 0);
                    acc_a[rt] = __builtin_amdgcn_mfma_f32_16x16x32_bf16(Ah, Bal[kc], acc_a[rt], 0, 0, 0);
                }
            }
            const float bev = be[n], bav = ba[n];
            #pragma unroll
            for (int rt = 0; rt < 4; ++rt) {
                #pragma unroll
                for (int rg = 0; rg < 4; ++rg) {
                    const int row = base + rt * 16 + quad * 4 + rg;
                    float2 ea;
                    ea.x = sigmoidf_fast(acc_e[rt][rg] + bev);
                    ea.y = tanhf_fast(acc_a[rt][rg] + bav);
                    ea_out[(size_t)row * DIM + n] = ea;
                }
            }
        }
    }
}

// ---------------------------------------------------------------------------
// Kernel C (r16): NO LDS. Per-thread global streaming with distance-8
// rolling register prefetch. Rationale: w4/ea have zero cross-thread reuse
// beyond wave-level broadcast (served by L1/L2); LDS staging cost = DMA +
// 16 barriers + vmcnt drains + LDS-pipe contention (est 152 cy/CU/step)
// with only 2 waves/SIMD to hide it. Direct global + PF=8 (~400 cy cover)
// lets waves free-run; only remaining cross-lane op is the DPP m-reduce.
// Grid is (b, ds) so the 4 ds-blocks of one batch land on ONE XCD
// (linear id = ds*64+b, 64%8==0) -> w[b] shared in that XCD's L2.
// ---------------------------------------------------------------------------
__global__ __launch_bounds__(512) void kC(const float* __restrict__ Mv0,
                                          const float* __restrict__ w_in,
                                          const float2* __restrict__ ea_in,
                                          float* __restrict__ rd) {
    const int tid = threadIdx.x;
    const int p  = tid & 15;
    const int dl = tid >> 4;          // 0..31
    const int b  = blockIdx.x;        // batch
    const int ds = blockIdx.y;        // d-chunk
    const int d  = ds * 32 + dl;
    const int m0 = p * 4;

    const float4* __restrict__ wsrc =
        reinterpret_cast<const float4*>(w_in + (size_t)b * LL * MM) + p;   // step t: wsrc[t*16]
    const float2* __restrict__ easrc = ea_in + (size_t)b * LL * DIM + d;   // step t: easrc[t*DIM]
    float* rp = rd + (size_t)b * LL * DIM + d;

    float Mv[4];
    #pragma unroll
    for (int j = 0; j < 4; ++j)
        Mv[j] = Mv0[(m0 + j) * DIM + d];

    constexpr int PF = 8;             // prefetch distance (steps)
    float4 wq[PF];
    float2 eq[PF];
    #pragma unroll
    for (int u = 0; u < PF; ++u) {
        wq[u] = wsrc[u * 16];
        eq[u] = easrc[(size_t)u * DIM];
    }

#define KC_STEP(W4, EA, T)                                                  \
    {                                                                       \
        float wv0 = (W4).x, wv1 = (W4).y, wv2 = (W4).z, wv3 = (W4).w;       \
        float e_c = (EA).x, a_c = (EA).y;                                   \
        float old0 = Mv[0], old1 = Mv[1], old2 = Mv[2], old3 = Mv[3];       \
        float pp0 = wv0 * old0;                                             \
        pp0 = fmaf(wv1, old1, pp0);                                         \
        float pp1 = wv2 * old2;                                             \
        pp1 = fmaf(wv3, old3, pp1);                                         \
        Mv[0] = fmaf(wv0, fmaf(-old0, e_c, a_c), old0);                     \
        Mv[1] = fmaf(wv1, fmaf(-old1, e_c, a_c), old1);                     \
        Mv[2] = fmaf(wv2, fmaf(-old2, e_c, a_c), old2);                     \
        Mv[3] = fmaf(wv3, fmaf(-old3, e_c, a_c), old3);                     \
        float part = pp0 + pp1;                                             \
        part += quad_swap1(part);                                           \
        part += quad_swap2(part);                                           \
        part += row_ror4(part);                                             \
        part += row_ror8(part);                                             \
        if (p == 0) rp[(size_t)(T) * DIM] = part;                           \
    }

    int t0 = 0;
    for (; t0 < LL - PF; t0 += PF) {
        #pragma unroll
        for (int j = 0; j < PF; ++j) {
            float4 w4 = wq[j];
            float2 ea = eq[j];
            // issue next-tile loads BEFORE compute (latency hides under VALU)
            wq[j] = wsrc[(t0 + PF + j) * 16];
            eq[j] = easrc[(size_t)(t0 + PF + j) * DIM];
            KC_STEP(w4, ea, t0 + j);
        }
    }
    #pragma unroll
    for (int j = 0; j < PF; ++j)
        KC_STEP(wq[j], eq[j], t0 + j);
#undef KC_STEP
}

// ---------------------------------------------------------------------------
// Kernel D (MFMA, A=hi only): f = tanh([rd,k]@Wf+bf); p = sigmoid(f@Wp+bp).
// 64 rows/block; rd staged via f2bf (hi), Ek gathered pre-converted.
// ---------------------------------------------------------------------------
__global__ __launch_bounds__(256) void kD(const int* __restrict__ q,
                                          const u16* __restrict__ ekbf,
                                          const u16* __restrict__ wfT_hi, const u16* __restrict__ wfT_lo,
                                          const float* __restrict__ bfv,
                                          const float* __restrict__ Wp, const float* __restrict__ bp,
                                          const float* __restrict__ rd,
                                          float* __restrict__ out) {
    __shared__ __align__(16) u16 xhi[4][16][264];   // 33792 B (fbuf overlays exactly)
    __shared__ float sred[64][4];
    const int tid = threadIdx.x;
    const int base = blockIdx.x * 64;
    const int row_l = tid >> 2;
    const int rts = row_l >> 4, ms = row_l & 15;
    const int d0 = (tid & 3) * 32;
    const int row = base + row_l;

    {   // x[:, 0:128) = rd -> bf16 hi
        const float* src = rd + (size_t)row * DIM + d0;
        #pragma unroll
        for (int c8 = 0; c8 < 4; ++c8) {
            float4 f0 = *reinterpret_cast<const float4*>(src + c8 * 8);
            float4 f1 = *reinterpret_cast<const float4*>(src + c8 * 8 + 4);
            float xs[8] = {f0.x, f0.y, f0.z, f0.w, f1.x, f1.y, f1.z, f1.w};
            bfrag h;
            #pragma unroll
            for (int j = 0; j < 8; ++j) h[j] = (short)f2bf(xs[j]);
            *reinterpret_cast<bfrag*>(&xhi[rts][ms][d0 + c8 * 8]) = h;
        }
    }
    {   // x[:, 128:256) = ekbf[q[row]] (already bf16)
        const u16* src = ekbf + (size_t)q[row] * DIM + d0;
        #pragma unroll
        for (int c8 = 0; c8 < 4; ++c8)
            *reinterpret_cast<bfrag*>(&xhi[rts][ms][128 + d0 + c8 * 8]) =
                *reinterpret_cast<const bfrag*>(src + c8 * 8);
    }
    __syncthreads();

    const int lane = tid & 63;
    const int wv = tid >> 6;
    const int nloc = lane & 15;
    const int quad = lane >> 4;
    float* fbuf = reinterpret_cast<float*>(&xhi[0][0][0]);   // overlay after sync

    f32x4 acc[2][4];
    #pragma unroll
    for (int dt = 0; dt < 2; ++dt)
        #pragma unroll
        for (int t = 0; t < 4; ++t) acc[dt][t] = 0.f;

    #pragma unroll
    for (int dt = 0; dt < 2; ++dt) {
        const int n = (wv * 2 + dt) * 16 + nloc;
        bfrag Bh[8], Bl[8];
        #pragma unroll
        for (int kc = 0; kc < 8; ++kc) {
            const int ko = kc * 32 + quad * 8;
            Bh[kc] = *reinterpret_cast<const bfrag*>(wfT_hi + n * 256 + ko);
            Bl[kc] = *reinterpret_cast<const bfrag*>(wfT_lo + n * 256 + ko);
        }
        #pragma unroll
        for (int rt = 0; rt < 4; ++rt) {
            #pragma unroll
            for (int kc = 0; kc < 8; ++kc) {
                const int ko = kc * 32 + quad * 8;
                bfrag Ah = *reinterpret_cast<const bfrag*>(&xhi[rt][nloc][ko]);
                acc[dt][rt] = __builtin_amdgcn_mfma_f32_16x16x32_bf16(Ah, Bh[kc], acc[dt][rt], 0, 0, 0);
                acc[dt][rt] = __builtin_amdgcn_mfma_f32_16x16x32_bf16(Ah, Bl[kc], acc[dt][rt], 0, 0, 0);
            }
        }
    }
    __syncthreads();   // LDS x reads done before fbuf overlay

    #pragma unroll
    for (int dt = 0; dt < 2; ++dt) {
        const int n = (wv * 2 + dt) * 16 + nloc;
        const float bfn = bfv[n], wpn = Wp[n];
        #pragma unroll
        for (int rt = 0; rt < 4; ++rt)
            #pragma unroll
            for (int rg = 0; rg < 4; ++rg)
                fbuf[(rt * 16 + quad * 4 + rg) * 132 + n] = tanhf_fast(acc[dt][rt][rg] + bfn) * wpn;
    }
    __syncthreads();

    {
        float s = 0.f;
        const int c = tid & 3;
        #pragma unroll
        for (int k = 0; k < 32; ++k) s += fbuf[row_l * 132 + c * 32 + k];
        sred[row_l][c] = s;
    }
    __syncthreads();
    if (tid < 64)
        out[base + tid] = sigmoidf_fast(sred[tid][0] + sred[tid][1] + sred[tid][2] + sred[tid][3] + bp[0]);
}

// ---------------------------------------------------------------------------
extern "C" void kernel_launch(void* const* d_in, const int* in_sizes, int n_in,
                              void* d_out, int out_size, void* d_ws, size_t ws_size,
                              hipStream_t stream) {
    const int*   q   = (const int*)d_in[0];
    const int*   r   = (const int*)d_in[1];
    const float* Ek  = (const float*)d_in[2];
    const float* Ev  = (const float*)d_in[3];
    const float* Mk  = (const float*)d_in[4];
    const float* Mv0 = (const float*)d_in[5];
    const float* We  = (const float*)d_in[6];
    const float* be  = (const float*)d_in[7];
    const float* Wa  = (const float*)d_in[8];
    const float* ba  = (const float*)d_in[9];
    const float* Wf  = (const float*)d_in[10];
    const float* bfv = (const float*)d_in[11];
    const float* Wp  = (const float*)d_in[12];
    const float* bp  = (const float*)d_in[13];
    float* out = (float*)d_out;

    float*  ws     = (float*)d_ws;
    float*  w_buf  = ws;                                      // 8 MB
    float2* ea_buf = (float2*)(w_buf + (size_t)NROWS * MM);   // 32 MB
    float*  rd     = (float*)(ea_buf + (size_t)NROWS * DIM);  // 16 MB

    // prepped bf16 data right after rd (~1.1 MB)
    u16* weT_hi = (u16*)(rd + (size_t)NROWS * DIM);
    u16* weT_lo = weT_hi + 16384;
    u16* waT_hi = weT_lo + 16384;
    u16* waT_lo = waT_hi + 16384;
    u16* wfT_hi = waT_lo + 16384;
    u16* wfT_lo = wfT_hi + 32768;
    u16* mkT_hi = wfT_lo + 32768;
    u16* mkT_lo = mkT_hi + 8192;
    u16* ekbf   = mkT_lo + 8192;      // 128000 u16
    u16* evbf   = ekbf + 128000;      // 256000 u16

    kP<<<dim3(128), 256, 0, stream>>>(We, Wa, Wf, Mk, Ek, Ev,
                                      weT_hi, weT_lo, waT_hi, waT_lo,
                                      wfT_hi, wfT_lo, mkT_hi, mkT_lo, ekbf, evbf);
    kAB<<<dim3(1024), 256, 0, stream>>>(q, r, ekbf, evbf, mkT_hi, mkT_lo,
                                        weT_hi, weT_lo, waT_hi, waT_lo,
                                        be, ba, w_buf, ea_buf);
    kC<<<dim3(BB, 4), 512, 0, stream>>>(Mv0, w_buf, ea_buf, rd);
    kD<<<dim3(NROWS / 64), 256, 0, stream>>>(q, ekbf, wfT_hi, wfT_lo, bfv, Wp, bp, rd, out);
}

// Round 3
// 181.038 us; speedup vs baseline: 1.0856x; 1.0856x over previous
//
#include <hip/hip_runtime.h>
#include <hip/hip_bf16.h>

#define NUM_C 1000
#define DIM   128
#define MM    64
#define BB    64
#define LL    512
#define NROWS (BB * LL)   // 32768

typedef unsigned short u16;
typedef unsigned int   u32;
typedef short bfrag __attribute__((ext_vector_type(8)));   // 8 bf16 (4 VGPRs)
typedef float f32x4 __attribute__((ext_vector_type(4)));   // MFMA acc
typedef unsigned uv2 __attribute__((ext_vector_type(2)));

__device__ __forceinline__ float sigmoidf_fast(float x) { return 1.f / (1.f + __expf(-x)); }
__device__ __forceinline__ float tanhf_fast(float x) { return 1.f - 2.f / (__expf(2.f * x) + 1.f); }

__device__ __forceinline__ u16 f2bf(float x) {            // RNE f32->bf16 bits
    u32 u = __float_as_uint(x);
    return (u16)((u + 0x7FFFu + ((u >> 16) & 1u)) >> 16);
}
__device__ __forceinline__ float bf2f(u16 h) { return __uint_as_float(((u32)h) << 16); }

// DPP quad_perm swaps + row rotates (VALU-only, verified rounds 5-14)
__device__ __forceinline__ float quad_swap1(float x) {    // dl ^ 1
    return __int_as_float(__builtin_amdgcn_mov_dpp(__float_as_int(x), 0xB1, 0xF, 0xF, true));
}
__device__ __forceinline__ float quad_swap2(float x) {    // dl ^ 2
    return __int_as_float(__builtin_amdgcn_mov_dpp(__float_as_int(x), 0x4E, 0xF, 0xF, true));
}
__device__ __forceinline__ float quad_rev(float x) {      // dl ^ 3
    return __int_as_float(__builtin_amdgcn_mov_dpp(__float_as_int(x), 0x1B, 0xF, 0xF, true));
}
__device__ __forceinline__ float row_ror4(float x) {
    return __int_as_float(__builtin_amdgcn_mov_dpp(__float_as_int(x), 0x124, 0xF, 0xF, true));
}
__device__ __forceinline__ float row_ror8(float x) {
    return __int_as_float(__builtin_amdgcn_mov_dpp(__float_as_int(x), 0x128, 0xF, 0xF, true));
}

// xor-16 / xor-32 lane sums, VALU-only via permlane*_swap (r.x + r.y trick:
// with both inputs = x, the output pair at lane i is {x[i], x[i^K]}).
__device__ __forceinline__ float xor16_sum(float x) {
#if __has_builtin(__builtin_amdgcn_permlane16_swap)
    uv2 r = __builtin_amdgcn_permlane16_swap(__float_as_uint(x), __float_as_uint(x), false, false);
    return __uint_as_float(r.x) + __uint_as_float(r.y);
#else
    return x + __int_as_float(__builtin_amdgcn_ds_swizzle(__float_as_int(x), 0x401F));
#endif
}
__device__ __forceinline__ float xor32_sum(float x) {
#if __has_builtin(__builtin_amdgcn_permlane32_swap)
    uv2 r = __builtin_amdgcn_permlane32_swap(__float_as_uint(x), __float_as_uint(x), false, false);
    return __uint_as_float(r.x) + __uint_as_float(r.y);
#else
    return x + __shfl_xor(x, 32);
#endif
}

// async global->LDS DMA, 16B per lane, LDS dest = wave-uniform base + lane*16
__device__ __forceinline__ void ld16(const void* g, void* l) {
    __builtin_amdgcn_global_load_lds(
        (const __attribute__((address_space(1))) unsigned int*)g,
        (__attribute__((address_space(3))) unsigned int*)l, 16, 0, 0);
}

// ---------------------------------------------------------------------------
// Prep: B-side weights as bf16 hi/lo ([n][k] transposed); A-side embeddings
// Ek/Ev pre-converted to bf16 hi ONCE (removes per-row conversion in kAB/kD).
// ---------------------------------------------------------------------------
__global__ __launch_bounds__(256) void kP(const float* __restrict__ We,
                                          const float* __restrict__ Wa,
                                          const float* __restrict__ Wf,
                                          const float* __restrict__ Mk,
                                          const float* __restrict__ Ek,
                                          const float* __restrict__ Ev,
                                          u16* weT_hi, u16* weT_lo,
                                          u16* waT_hi, u16* waT_lo,
                                          u16* wfT_hi, u16* wfT_lo,
                                          u16* mkT_hi, u16* mkT_lo,
                                          u16* ekbf, u16* evbf) {
    int idx = blockIdx.x * 256 + threadIdx.x;   // 0..32767
    if (idx < 128 * 128) {
        int n = idx >> 7, k = idx & 127;
        float we = We[k * DIM + n];
        u16 h = f2bf(we);
        weT_hi[idx] = h; weT_lo[idx] = f2bf(we - bf2f(h));
        float wa = Wa[k * DIM + n];
        u16 h2 = f2bf(wa);
        waT_hi[idx] = h2; waT_lo[idx] = f2bf(wa - bf2f(h2));
    }
    if (idx < 64 * 128) {
        float mk = Mk[idx];
        u16 h = f2bf(mk);
        mkT_hi[idx] = h; mkT_lo[idx] = f2bf(mk - bf2f(h));
    }
    {
        int n = idx >> 8, k = idx & 255;
        float wf = Wf[k * DIM + n];
        u16 h = f2bf(wf);
        wfT_hi[idx] = h; wfT_lo[idx] = f2bf(wf - bf2f(h));
    }
    for (int i = idx; i < NUM_C * DIM; i += 32768) ekbf[i] = f2bf(Ek[i]);
    for (int i = idx; i < 2 * NUM_C * DIM; i += 32768) evbf[i] = f2bf(Ev[i]);
}

// ---------------------------------------------------------------------------
// Fused kAB (MFMA, A=bf16-hi only, B=hi+lo). Blocks [0,512): kA role.
// Blocks [512,1024): kB role. 64 rows/block; staging = pure u16 gather.
// ---------------------------------------------------------------------------
__global__ __launch_bounds__(256) void kAB(const int* __restrict__ q,
                                           const int* __restrict__ r,
                                           const u16* __restrict__ ekbf,
                                           const u16* __restrict__ evbf,
                                           const u16* __restrict__ mkT_hi, const u16* __restrict__ mkT_lo,
                                           const u16* __restrict__ weT_hi, const u16* __restrict__ weT_lo,
                                           const u16* __restrict__ waT_hi, const u16* __restrict__ waT_lo,
                                           const float* __restrict__ be, const float* __restrict__ ba,
                                           float* __restrict__ w_out,
                                           float2* __restrict__ ea_out) {
    __shared__ __align__(16) u16 shi[4][16][136];
    __shared__ float slab[4][64];
    const int tid = threadIdx.x;
    const int lane = tid & 63;
    const int wv = tid >> 6;
    const int nloc = lane & 15;
    const int quad = lane >> 4;

    if (blockIdx.x < 512) {
        // ---------------- kA role ----------------
        const int base = blockIdx.x * 64;
        {   // stage k = ekbf[q] (already bf16)
            const int row_l = tid >> 2;
            const int rts = row_l >> 4, ms = row_l & 15;
            const int d0 = (tid & 3) * 32;
            const u16* src = ekbf + (size_t)q[base + row_l] * DIM + d0;
            #pragma unroll
            for (int c8 = 0; c8 < 4; ++c8)
                *reinterpret_cast<bfrag*>(&shi[rts][ms][d0 + c8 * 8]) =
                    *reinterpret_cast<const bfrag*>(src + c8 * 8);
        }
        __syncthreads();

        const int n = wv * 16 + nloc;      // m index
        bfrag Bh[4], Bl[4];
        #pragma unroll
        for (int kc = 0; kc < 4; ++kc) {
            const int ko = kc * 32 + quad * 8;
            Bh[kc] = *reinterpret_cast<const bfrag*>(mkT_hi + n * DIM + ko);
            Bl[kc] = *reinterpret_cast<const bfrag*>(mkT_lo + n * DIM + ko);
        }

        f32x4 acc[4];
        #pragma unroll
        for (int t = 0; t < 4; ++t) acc[t] = 0.f;

        #pragma unroll
        for (int rt = 0; rt < 4; ++rt) {
            #pragma unroll
            for (int kc = 0; kc < 4; ++kc) {
                const int ko = kc * 32 + quad * 8;
                bfrag Ah = *reinterpret_cast<const bfrag*>(&shi[rt][nloc][ko]);
                acc[rt] = __builtin_amdgcn_mfma_f32_16x16x32_bf16(Ah, Bh[kc], acc[rt], 0, 0, 0);
                acc[rt] = __builtin_amdgcn_mfma_f32_16x16x32_bf16(Ah, Bl[kc], acc[rt], 0, 0, 0);
            }
        }

        float ex[4][4];
        #pragma unroll
        for (int rt = 0; rt < 4; ++rt) {
            #pragma unroll
            for (int rg = 0; rg < 4; ++rg) {
                float e = __expf(acc[rt][rg]);
                ex[rt][rg] = e;
                float s = e;
                s += __shfl_xor(s, 1);
                s += __shfl_xor(s, 2);
                s += __shfl_xor(s, 4);
                s += __shfl_xor(s, 8);
                if (nloc == 0) slab[wv][rt * 16 + quad * 4 + rg] = s;
            }
        }
        __syncthreads();

        #pragma unroll
        for (int rt = 0; rt < 4; ++rt) {
            #pragma unroll
            for (int rg = 0; rg < 4; ++rg) {
                const int row = rt * 16 + quad * 4 + rg;
                float tot = slab[0][row] + slab[1][row] + slab[2][row] + slab[3][row];
                w_out[(size_t)(base + row) * MM + n] = ex[rt][rg] / tot;
            }
        }
    } else {
        // ---------------- kB role ----------------
        const int base = (blockIdx.x - 512) * 64;
        {   // stage v = evbf[x] (already bf16)
            const int row_l = tid >> 2;
            const int rts = row_l >> 4, ms = row_l & 15;
            const int d0 = (tid & 3) * 32;
            const int row = base + row_l;
            const int x = q[row] + NUM_C * r[row];
            const u16* src = evbf + (size_t)x * DIM + d0;
            #pragma unroll
            for (int c8 = 0; c8 < 4; ++c8)
                *reinterpret_cast<bfrag*>(&shi[rts][ms][d0 + c8 * 8]) =
                    *reinterpret_cast<const bfrag*>(src + c8 * 8);
        }
        __syncthreads();

        #pragma unroll
        for (int dt = 0; dt < 2; ++dt) {
            const int n = (wv * 2 + dt) * 16 + nloc;
            bfrag Beh[4], Bel[4], Bah[4], Bal[4];
            #pragma unroll
            for (int kc = 0; kc < 4; ++kc) {
                const int ko = kc * 32 + quad * 8;
                Beh[kc] = *reinterpret_cast<const bfrag*>(weT_hi + n * DIM + ko);
                Bel[kc] = *reinterpret_cast<const bfrag*>(weT_lo + n * DIM + ko);
                Bah[kc] = *reinterpret_cast<const bfrag*>(waT_hi + n * DIM + ko);
                Bal[kc] = *reinterpret_cast<const bfrag*>(waT_lo + n * DIM + ko);
            }
            f32x4 acc_e[4], acc_a[4];
            #pragma unroll
            for (int t = 0; t < 4; ++t) { acc_e[t] = 0.f; acc_a[t] = 0.f; }

            #pragma unroll
            for (int rt = 0; rt < 4; ++rt) {
                #pragma unroll
                for (int kc = 0; kc < 4; ++kc) {
                    const int ko = kc * 32 + quad * 8;
                    bfrag Ah = *reinterpret_cast<const bfrag*>(&shi[rt][nloc][ko]);
                    acc_e[rt] = __builtin_amdgcn_mfma_f32_16x16x32_bf16(Ah, Beh[kc], acc_e[rt], 0, 0, 0);
                    acc_a[rt] = __builtin_amdgcn_mfma_f32_16x16x32_bf16(Ah, Bah[kc], acc_a[rt], 0, 0, 0);
                    acc_e[rt] = __builtin_amdgcn_mfma_f32_16x16x32_bf16(Ah, Bel[kc], acc_e[rt], 0, 0, 0);
                    acc_a[rt] = __builtin_amdgcn_mfma_f32_16x16x32_bf16(Ah, Bal[kc], acc_a[rt], 0, 0, 0);
                }
            }
            const float bev = be[n], bav = ba[n];
            #pragma unroll
            for (int rt = 0; rt < 4; ++rt) {
                #pragma unroll
                for (int rg = 0; rg < 4; ++rg) {
                    const int row = base + rt * 16 + quad * 4 + rg;
                    float2 ea;
                    ea.x = sigmoidf_fast(acc_e[rt][rg] + bev);
                    ea.y = tanhf_fast(acc_a[rt][rg] + bav);
                    ea_out[(size_t)row * DIM + n] = ea;
                }
            }
        }
    }
}

// ---------------------------------------------------------------------------
// Kernel C (r17): LDS DMA staging kept (r16 showed per-step VMEM loads cost
// ~2x), but the per-step LDS reads are made duplication-free:
//  - lane = p*4 + dl (p = m-group 0..15, dl = d 0..3 within wave).
//  - w read: ds_read_b32, lane reads w[t][lane] (linear, 2-way alias = free,
//    5.8 cy vs 12 cy for the old 4x-duplicated b128).
//  - quad assembles w4 via 3 quad_perm DPP movs; Mv slot j holds m=4p+(dl^j)
//    (permuted at init) so no selects are needed.
//  - m-reduce over stride-4 lanes: row_ror4/8 then permlane16/32_swap sums.
//  - ds-split 8 (16 d per 256-thread block): 512 blocks = 2 blocks/CU,
//    independent barrier domains. Grid (b, ds) keeps a batch on one XCD.
// Budget: LDS ~102 cy/CU-step (was 152), VALU ~100 cy/SIMD-step.
// ---------------------------------------------------------------------------
__device__ __forceinline__ void scan32(const float* wb, const float2* eab,
                                       int lane, int jcol, float (&Mv)[4],
                                       float* rp, int t0, bool wr) {
    constexpr int PF = 4;
    float  wq[PF];
    float2 eq[PF];
    #pragma unroll
    for (int u = 0; u < PF; ++u) {
        wq[u] = wb[u * 64 + lane];
        eq[u] = eab[u * 16 + jcol];
    }
    #pragma unroll
    for (int u = 0; u < 32; ++u) {
        float  x  = wq[u & 3];
        float2 ea = eq[u & 3];
        if (u + PF < 32) {
            wq[u & 3] = wb[(u + PF) * 64 + lane];
            eq[u & 3] = eab[(u + PF) * 16 + jcol];
        }
        float x1 = quad_swap1(x);
        float x2 = quad_swap2(x);
        float x3 = quad_rev(x);
        float e_c = ea.x, a_c = ea.y;

        float o0 = Mv[0], o1 = Mv[1], o2 = Mv[2], o3 = Mv[3];
        float pp0 = x * o0;
        pp0 = fmaf(x1, o1, pp0);
        float pp1 = x2 * o2;
        pp1 = fmaf(x3, o3, pp1);
        Mv[0] = fmaf(x , fmaf(-o0, e_c, a_c), o0);
        Mv[1] = fmaf(x1, fmaf(-o1, e_c, a_c), o1);
        Mv[2] = fmaf(x2, fmaf(-o2, e_c, a_c), o2);
        Mv[3] = fmaf(x3, fmaf(-o3, e_c, a_c), o3);
        float part = pp0 + pp1;

        part += row_ror4(part);
        part += row_ror8(part);       // in-row: sums the 4 p-groups of the row
        part = xor16_sum(part);       // combine row pairs
        part = xor32_sum(part);       // combine halves -> full 16-p (64-m) sum
        if (wr) rp[(size_t)(t0 + u) * DIM] = part;
    }
}

__global__ __launch_bounds__(256) void kC(const float* __restrict__ Mv0,
                                          const float* __restrict__ w_in,
                                          const float2* __restrict__ ea_in,
                                          float* __restrict__ rd) {
    __shared__ __align__(16) float  wlds[2][32][64];    // 16 KB
    __shared__ __align__(16) float2 ealds[2][32][16];   // 8 KB
    const int tid  = threadIdx.x;
    const int lane = tid & 63;
    const int wv   = tid >> 6;        // 0..3
    const int p    = lane >> 2;       // m-group 0..15
    const int dl   = lane & 3;        // d-within-quad
    const int b    = blockIdx.x;      // batch
    const int ds   = blockIdx.y;      // d-chunk 0..7
    const int jcol = wv * 4 + dl;     // 0..15: d within block slice
    const int d    = ds * 16 + jcol;

    const char* wsrc  = (const char*)(w_in + (size_t)b * LL * MM);
    const char* easrc = (const char*)(ea_in + (size_t)b * LL * DIM + ds * 16);
    float* rp = rd + (size_t)b * LL * DIM + d;

    auto dma = [&](int c, int bufi) {
        const char* wt = wsrc + (size_t)c * 8192;
        char* wl = (char*)&wlds[bufi][0][0];
        char* el = (char*)&ealds[bufi][0][0];
        const int off = tid * 16;                         // 0..4095
        ld16(wt + off, wl + off);                         // w: 8 KB in 2 rounds
        ld16(wt + 4096 + off, wl + 4096 + off);
        const int tl = tid >> 3, wi = (tid & 7) * 16;     // ea: 128B rows, 1KB stride
        ld16(easrc + (size_t)(c * 32 + tl) * (DIM * 8) + wi, el + off);
    };

    dma(0, 0);

    float Mv[4];
    #pragma unroll
    for (int j = 0; j < 4; ++j)
        Mv[j] = Mv0[(size_t)(p * 4 + (dl ^ j)) * DIM + d];   // slot j <-> m=4p+(dl^j)

    __builtin_amdgcn_s_waitcnt(0x0F70);   // vmcnt(0): tile-0 DMA + Mv loads done
    __syncthreads();

    const bool wr = (lane < 4);           // p==0 lanes store their d
    int buf = 0;
    for (int c = 0; c < LL / 32; ++c) {
        if (c + 1 < LL / 32) dma(c + 1, buf ^ 1);
        scan32(&wlds[buf][0][0], &ealds[buf][0][0], lane, jcol, Mv, rp, c * 32, wr);
        if (c + 1 < LL / 32) {
            __builtin_amdgcn_s_waitcnt(0x8F70);   // vmcnt(32): 3 DMAs retired, stores may fly
            __syncthreads();
            buf ^= 1;
        }
    }
}

// ---------------------------------------------------------------------------
// Kernel D (MFMA, A=hi only): f = tanh([rd,k]@Wf+bf); p = sigmoid(f@Wp+bp).
// 64 rows/block; rd staged via f2bf (hi), Ek gathered pre-converted.
// ---------------------------------------------------------------------------
__global__ __launch_bounds__(256) void kD(const int* __restrict__ q,
                                          const u16* __restrict__ ekbf,
                                          const u16* __restrict__ wfT_hi, const u16* __restrict__ wfT_lo,
                                          const float* __restrict__ bfv,
                                          const float* __restrict__ Wp, const float* __restrict__ bp,
                                          const float* __restrict__ rd,
                                          float* __restrict__ out) {
    __shared__ __align__(16) u16 xhi[4][16][264];   // 33792 B (fbuf overlays exactly)
    __shared__ float sred[64][4];
    const int tid = threadIdx.x;
    const int base = blockIdx.x * 64;
    const int row_l = tid >> 2;
    const int rts = row_l >> 4, ms = row_l & 15;
    const int d0 = (tid & 3) * 32;
    const int row = base + row_l;

    {   // x[:, 0:128) = rd -> bf16 hi
        const float* src = rd + (size_t)row * DIM + d0;
        #pragma unroll
        for (int c8 = 0; c8 < 4; ++c8) {
            float4 f0 = *reinterpret_cast<const float4*>(src + c8 * 8);
            float4 f1 = *reinterpret_cast<const float4*>(src + c8 * 8 + 4);
            float xs[8] = {f0.x, f0.y, f0.z, f0.w, f1.x, f1.y, f1.z, f1.w};
            bfrag h;
            #pragma unroll
            for (int j = 0; j < 8; ++j) h[j] = (short)f2bf(xs[j]);
            *reinterpret_cast<bfrag*>(&xhi[rts][ms][d0 + c8 * 8]) = h;
        }
    }
    {   // x[:, 128:256) = ekbf[q[row]] (already bf16)
        const u16* src = ekbf + (size_t)q[row] * DIM + d0;
        #pragma unroll
        for (int c8 = 0; c8 < 4; ++c8)
            *reinterpret_cast<bfrag*>(&xhi[rts][ms][128 + d0 + c8 * 8]) =
                *reinterpret_cast<const bfrag*>(src + c8 * 8);
    }
    __syncthreads();

    const int lane = tid & 63;
    const int wv = tid >> 6;
    const int nloc = lane & 15;
    const int quad = lane >> 4;
    float* fbuf = reinterpret_cast<float*>(&xhi[0][0][0]);   // overlay after sync

    f32x4 acc[2][4];
    #pragma unroll
    for (int dt = 0; dt < 2; ++dt)
        #pragma unroll
        for (int t = 0; t < 4; ++t) acc[dt][t] = 0.f;

    #pragma unroll
    for (int dt = 0; dt < 2; ++dt) {
        const int n = (wv * 2 + dt) * 16 + nloc;
        bfrag Bh[8], Bl[8];
        #pragma unroll
        for (int kc = 0; kc < 8; ++kc) {
            const int ko = kc * 32 + quad * 8;
            Bh[kc] = *reinterpret_cast<const bfrag*>(wfT_hi + n * 256 + ko);
            Bl[kc] = *reinterpret_cast<const bfrag*>(wfT_lo + n * 256 + ko);
        }
        #pragma unroll
        for (int rt = 0; rt < 4; ++rt) {
            #pragma unroll
            for (int kc = 0; kc < 8; ++kc) {
                const int ko = kc * 32 + quad * 8;
                bfrag Ah = *reinterpret_cast<const bfrag*>(&xhi[rt][nloc][ko]);
                acc[dt][rt] = __builtin_amdgcn_mfma_f32_16x16x32_bf16(Ah, Bh[kc], acc[dt][rt], 0, 0, 0);
                acc[dt][rt] = __builtin_amdgcn_mfma_f32_16x16x32_bf16(Ah, Bl[kc], acc[dt][rt], 0, 0, 0);
            }
        }
    }
    __syncthreads();   // LDS x reads done before fbuf overlay

    #pragma unroll
    for (int dt = 0; dt < 2; ++dt) {
        const int n = (wv * 2 + dt) * 16 + nloc;
        const float bfn = bfv[n], wpn = Wp[n];
        #pragma unroll
        for (int rt = 0; rt < 4; ++rt)
            #pragma unroll
            for (int rg = 0; rg < 4; ++rg)
                fbuf[(rt * 16 + quad * 4 + rg) * 132 + n] = tanhf_fast(acc[dt][rt][rg] + bfn) * wpn;
    }
    __syncthreads();

    {
        float s = 0.f;
        const int c = tid & 3;
        #pragma unroll
        for (int k = 0; k < 32; ++k) s += fbuf[row_l * 132 + c * 32 + k];
        sred[row_l][c] = s;
    }
    __syncthreads();
    if (tid < 64)
        out[base + tid] = sigmoidf_fast(sred[tid][0] + sred[tid][1] + sred[tid][2] + sred[tid][3] + bp[0]);
}

// ---------------------------------------------------------------------------
extern "C" void kernel_launch(void* const* d_in, const int* in_sizes, int n_in,
                              void* d_out, int out_size, void* d_ws, size_t ws_size,
                              hipStream_t stream) {
    const int*   q   = (const int*)d_in[0];
    const int*   r   = (const int*)d_in[1];
    const float* Ek  = (const float*)d_in[2];
    const float* Ev  = (const float*)d_in[3];
    const float* Mk  = (const float*)d_in[4];
    const float* Mv0 = (const float*)d_in[5];
    const float* We  = (const float*)d_in[6];
    const float* be  = (const float*)d_in[7];
    const float* Wa  = (const float*)d_in[8];
    const float* ba  = (const float*)d_in[9];
    const float* Wf  = (const float*)d_in[10];
    const float* bfv = (const float*)d_in[11];
    const float* Wp  = (const float*)d_in[12];
    const float* bp  = (const float*)d_in[13];
    float* out = (float*)d_out;

    float*  ws     = (float*)d_ws;
    float*  w_buf  = ws;                                      // 8 MB
    float2* ea_buf = (float2*)(w_buf + (size_t)NROWS * MM);   // 32 MB
    float*  rd     = (float*)(ea_buf + (size_t)NROWS * DIM);  // 16 MB

    // prepped bf16 data right after rd (~1.1 MB)
    u16* weT_hi = (u16*)(rd + (size_t)NROWS * DIM);
    u16* weT_lo = weT_hi + 16384;
    u16* waT_hi = weT_lo + 16384;
    u16* waT_lo = waT_hi + 16384;
    u16* wfT_hi = waT_lo + 16384;
    u16* wfT_lo = wfT_hi + 32768;
    u16* mkT_hi = wfT_lo + 32768;
    u16* mkT_lo = mkT_hi + 8192;
    u16* ekbf   = mkT_lo + 8192;      // 128000 u16
    u16* evbf   = ekbf + 128000;      // 256000 u16

    kP<<<dim3(128), 256, 0, stream>>>(We, Wa, Wf, Mk, Ek, Ev,
                                      weT_hi, weT_lo, waT_hi, waT_lo,
                                      wfT_hi, wfT_lo, mkT_hi, mkT_lo, ekbf, evbf);
    kAB<<<dim3(1024), 256, 0, stream>>>(q, r, ekbf, evbf, mkT_hi, mkT_lo,
                                        weT_hi, weT_lo, waT_hi, waT_lo,
                                        be, ba, w_buf, ea_buf);
    kC<<<dim3(BB, 8), 256, 0, stream>>>(Mv0, w_buf, ea_buf, rd);
    kD<<<dim3(NROWS / 64), 256, 0, stream>>>(q, ekbf, wfT_hi, wfT_lo, bfv, Wp, bp, rd, out);
}

// Round 4
// 178.543 us; speedup vs baseline: 1.1008x; 1.0140x over previous
//
#include <hip/hip_runtime.h>
#include <hip/hip_bf16.h>

#define NUM_C 1000
#define DIM   128
#define MM    64
#define BB    64
#define LL    512
#define NROWS (BB * LL)   // 32768

typedef unsigned short u16;
typedef unsigned int   u32;
typedef short bfrag __attribute__((ext_vector_type(8)));   // 8 bf16 (4 VGPRs)
typedef float f32x4 __attribute__((ext_vector_type(4)));   // MFMA acc

__device__ __forceinline__ float sigmoidf_fast(float x) { return 1.f / (1.f + __expf(-x)); }
__device__ __forceinline__ float tanhf_fast(float x) { return 1.f - 2.f / (__expf(2.f * x) + 1.f); }

__device__ __forceinline__ u16 f2bf(float x) {            // RNE f32->bf16 bits
    u32 u = __float_as_uint(x);
    return (u16)((u + 0x7FFFu + ((u >> 16) & 1u)) >> 16);
}
__device__ __forceinline__ float bf2f(u16 h) { return __uint_as_float(((u32)h) << 16); }

// DPP quad_perm swaps + row rotates (VALU-only, verified rounds 5-14)
__device__ __forceinline__ float quad_swap1(float x) {
    return __int_as_float(__builtin_amdgcn_mov_dpp(__float_as_int(x), 0xB1, 0xF, 0xF, true));
}
__device__ __forceinline__ float quad_swap2(float x) {
    return __int_as_float(__builtin_amdgcn_mov_dpp(__float_as_int(x), 0x4E, 0xF, 0xF, true));
}
__device__ __forceinline__ float row_ror4(float x) {
    return __int_as_float(__builtin_amdgcn_mov_dpp(__float_as_int(x), 0x124, 0xF, 0xF, true));
}
__device__ __forceinline__ float row_ror8(float x) {
    return __int_as_float(__builtin_amdgcn_mov_dpp(__float_as_int(x), 0x128, 0xF, 0xF, true));
}

// async global->LDS DMA, 16B per lane, LDS dest = wave-uniform base + lane*16
__device__ __forceinline__ void ld16(const void* g, void* l) {
    __builtin_amdgcn_global_load_lds(
        (const __attribute__((address_space(1))) unsigned int*)g,
        (__attribute__((address_space(3))) unsigned int*)l, 16, 0, 0);
}

// ---------------------------------------------------------------------------
// Prep: B-side weights as bf16 hi/lo ([n][k] transposed); A-side embeddings
// Ek/Ev pre-converted to bf16 hi ONCE (removes per-row conversion in kAB/kD).
// ---------------------------------------------------------------------------
__global__ __launch_bounds__(256) void kP(const float* __restrict__ We,
                                          const float* __restrict__ Wa,
                                          const float* __restrict__ Wf,
                                          const float* __restrict__ Mk,
                                          const float* __restrict__ Ek,
                                          const float* __restrict__ Ev,
                                          u16* weT_hi, u16* weT_lo,
                                          u16* waT_hi, u16* waT_lo,
                                          u16* wfT_hi, u16* wfT_lo,
                                          u16* mkT_hi, u16* mkT_lo,
                                          u16* ekbf, u16* evbf) {
    int idx = blockIdx.x * 256 + threadIdx.x;   // 0..32767
    if (idx < 128 * 128) {
        int n = idx >> 7, k = idx & 127;
        float we = We[k * DIM + n];
        u16 h = f2bf(we);
        weT_hi[idx] = h; weT_lo[idx] = f2bf(we - bf2f(h));
        float wa = Wa[k * DIM + n];
        u16 h2 = f2bf(wa);
        waT_hi[idx] = h2; waT_lo[idx] = f2bf(wa - bf2f(h2));
    }
    if (idx < 64 * 128) {
        float mk = Mk[idx];
        u16 h = f2bf(mk);
        mkT_hi[idx] = h; mkT_lo[idx] = f2bf(mk - bf2f(h));
    }
    {
        int n = idx >> 8, k = idx & 255;
        float wf = Wf[k * DIM + n];
        u16 h = f2bf(wf);
        wfT_hi[idx] = h; wfT_lo[idx] = f2bf(wf - bf2f(h));
    }
    for (int i = idx; i < NUM_C * DIM; i += 32768) ekbf[i] = f2bf(Ek[i]);
    for (int i = idx; i < 2 * NUM_C * DIM; i += 32768) evbf[i] = f2bf(Ev[i]);
}

// ---------------------------------------------------------------------------
// Fused kAB (MFMA, A=bf16-hi only, B=hi+lo). Blocks [0,512): kA role.
// Blocks [512,1024): kB role. 64 rows/block; staging = pure u16 gather.
// r18: outputs compressed -- w as bf16 u16, (e,a) packed as u32 (2x bf16).
// Halves kAB store traffic and kC's LDS read width.
// ---------------------------------------------------------------------------
__global__ __launch_bounds__(256) void kAB(const int* __restrict__ q,
                                           const int* __restrict__ r,
                                           const u16* __restrict__ ekbf,
                                           const u16* __restrict__ evbf,
                                           const u16* __restrict__ mkT_hi, const u16* __restrict__ mkT_lo,
                                           const u16* __restrict__ weT_hi, const u16* __restrict__ weT_lo,
                                           const u16* __restrict__ waT_hi, const u16* __restrict__ waT_lo,
                                           const float* __restrict__ be, const float* __restrict__ ba,
                                           u16* __restrict__ w_out,
                                           u32* __restrict__ ea_out) {
    __shared__ __align__(16) u16 shi[4][16][136];
    __shared__ float slab[4][64];
    const int tid = threadIdx.x;
    const int lane = tid & 63;
    const int wv = tid >> 6;
    const int nloc = lane & 15;
    const int quad = lane >> 4;

    if (blockIdx.x < 512) {
        // ---------------- kA role ----------------
        const int base = blockIdx.x * 64;
        {   // stage k = ekbf[q] (already bf16)
            const int row_l = tid >> 2;
            const int rts = row_l >> 4, ms = row_l & 15;
            const int d0 = (tid & 3) * 32;
            const u16* src = ekbf + (size_t)q[base + row_l] * DIM + d0;
            #pragma unroll
            for (int c8 = 0; c8 < 4; ++c8)
                *reinterpret_cast<bfrag*>(&shi[rts][ms][d0 + c8 * 8]) =
                    *reinterpret_cast<const bfrag*>(src + c8 * 8);
        }
        __syncthreads();

        const int n = wv * 16 + nloc;      // m index
        bfrag Bh[4], Bl[4];
        #pragma unroll
        for (int kc = 0; kc < 4; ++kc) {
            const int ko = kc * 32 + quad * 8;
            Bh[kc] = *reinterpret_cast<const bfrag*>(mkT_hi + n * DIM + ko);
            Bl[kc] = *reinterpret_cast<const bfrag*>(mkT_lo + n * DIM + ko);
        }

        f32x4 acc[4];
        #pragma unroll
        for (int t = 0; t < 4; ++t) acc[t] = 0.f;

        #pragma unroll
        for (int rt = 0; rt < 4; ++rt) {
            #pragma unroll
            for (int kc = 0; kc < 4; ++kc) {
                const int ko = kc * 32 + quad * 8;
                bfrag Ah = *reinterpret_cast<const bfrag*>(&shi[rt][nloc][ko]);
                acc[rt] = __builtin_amdgcn_mfma_f32_16x16x32_bf16(Ah, Bh[kc], acc[rt], 0, 0, 0);
                acc[rt] = __builtin_amdgcn_mfma_f32_16x16x32_bf16(Ah, Bl[kc], acc[rt], 0, 0, 0);
            }
        }

        float ex[4][4];
        #pragma unroll
        for (int rt = 0; rt < 4; ++rt) {
            #pragma unroll
            for (int rg = 0; rg < 4; ++rg) {
                float e = __expf(acc[rt][rg]);
                ex[rt][rg] = e;
                float s = e;
                s += __shfl_xor(s, 1);
                s += __shfl_xor(s, 2);
                s += __shfl_xor(s, 4);
                s += __shfl_xor(s, 8);
                if (nloc == 0) slab[wv][rt * 16 + quad * 4 + rg] = s;
            }
        }
        __syncthreads();

        #pragma unroll
        for (int rt = 0; rt < 4; ++rt) {
            #pragma unroll
            for (int rg = 0; rg < 4; ++rg) {
                const int row = rt * 16 + quad * 4 + rg;
                float tot = slab[0][row] + slab[1][row] + slab[2][row] + slab[3][row];
                w_out[(size_t)(base + row) * MM + n] = f2bf(ex[rt][rg] / tot);
            }
        }
    } else {
        // ---------------- kB role ----------------
        const int base = (blockIdx.x - 512) * 64;
        {   // stage v = evbf[x] (already bf16)
            const int row_l = tid >> 2;
            const int rts = row_l >> 4, ms = row_l & 15;
            const int d0 = (tid & 3) * 32;
            const int row = base + row_l;
            const int x = q[row] + NUM_C * r[row];
            const u16* src = evbf + (size_t)x * DIM + d0;
            #pragma unroll
            for (int c8 = 0; c8 < 4; ++c8)
                *reinterpret_cast<bfrag*>(&shi[rts][ms][d0 + c8 * 8]) =
                    *reinterpret_cast<const bfrag*>(src + c8 * 8);
        }
        __syncthreads();

        #pragma unroll
        for (int dt = 0; dt < 2; ++dt) {
            const int n = (wv * 2 + dt) * 16 + nloc;
            bfrag Beh[4], Bel[4], Bah[4], Bal[4];
            #pragma unroll
            for (int kc = 0; kc < 4; ++kc) {
                const int ko = kc * 32 + quad * 8;
                Beh[kc] = *reinterpret_cast<const bfrag*>(weT_hi + n * DIM + ko);
                Bel[kc] = *reinterpret_cast<const bfrag*>(weT_lo + n * DIM + ko);
                Bah[kc] = *reinterpret_cast<const bfrag*>(waT_hi + n * DIM + ko);
                Bal[kc] = *reinterpret_cast<const bfrag*>(waT_lo + n * DIM + ko);
            }
            f32x4 acc_e[4], acc_a[4];
            #pragma unroll
            for (int t = 0; t < 4; ++t) { acc_e[t] = 0.f; acc_a[t] = 0.f; }

            #pragma unroll
            for (int rt = 0; rt < 4; ++rt) {
                #pragma unroll
                for (int kc = 0; kc < 4; ++kc) {
                    const int ko = kc * 32 + quad * 8;
                    bfrag Ah = *reinterpret_cast<const bfrag*>(&shi[rt][nloc][ko]);
                    acc_e[rt] = __builtin_amdgcn_mfma_f32_16x16x32_bf16(Ah, Beh[kc], acc_e[rt], 0, 0, 0);
                    acc_a[rt] = __builtin_amdgcn_mfma_f32_16x16x32_bf16(Ah, Bah[kc], acc_a[rt], 0, 0, 0);
                    acc_e[rt] = __builtin_amdgcn_mfma_f32_16x16x32_bf16(Ah, Bel[kc], acc_e[rt], 0, 0, 0);
                    acc_a[rt] = __builtin_amdgcn_mfma_f32_16x16x32_bf16(Ah, Bal[kc], acc_a[rt], 0, 0, 0);
                }
            }
            const float bev = be[n], bav = ba[n];
            #pragma unroll
            for (int rt = 0; rt < 4; ++rt) {
                #pragma unroll
                for (int rg = 0; rg < 4; ++rg) {
                    const int row = base + rt * 16 + quad * 4 + rg;
                    float ev = sigmoidf_fast(acc_e[rt][rg] + bev);
                    float av = tanhf_fast(acc_a[rt][rg] + bav);
                    ea_out[(size_t)row * DIM + n] = (u32)f2bf(ev) | ((u32)f2bf(av) << 16);
                }
            }
        }
    }
}

// ---------------------------------------------------------------------------
// Kernel C (r18 = r15 structure + bf16-compressed tiles):
//  - w tile: 32 steps x 64 m x bf16 = 4 KB; lane reads ds_read_b64 (4 m, ~7cy
//    vs 12 for f32 b128). ea tile: 32 x 32 x u32(packed e,a) = 4 KB; lane
//    reads ds_read_b32 (~5.8cy vs 7). Per-wave LDS 19 -> 12.8 cy/step.
//  - DMA per tile: 8 wave-inst (was 24): half the block stages w, half ea.
//  - Unpack = shift/and (+6 VALU/step). Everything else identical to r15.
// ---------------------------------------------------------------------------
__device__ __forceinline__ void scan32(const u16* wb, const u32* eab,
                                       int m0, int dl, int p, int t0,
                                       float (&Mv)[4], float* rp) {
    uint2 wq[4];
    u32   eq[4];
    #pragma unroll
    for (int u = 0; u < 4; ++u) {
        wq[u] = *reinterpret_cast<const uint2*>(wb + u * 64 + m0);
        eq[u] = eab[u * 32 + dl];
    }
    #pragma unroll
    for (int u = 0; u < 32; ++u) {
        uint2 wp = wq[u & 3];
        u32   ep = eq[u & 3];
        if (u + 4 < 32) {
            wq[u & 3] = *reinterpret_cast<const uint2*>(wb + (u + 4) * 64 + m0);
            eq[u & 3] = eab[(u + 4) * 32 + dl];
        }
        float wv0 = __uint_as_float(wp.x << 16);
        float wv1 = __uint_as_float(wp.x & 0xffff0000u);
        float wv2 = __uint_as_float(wp.y << 16);
        float wv3 = __uint_as_float(wp.y & 0xffff0000u);
        float e_c = __uint_as_float(ep << 16);
        float a_c = __uint_as_float(ep & 0xffff0000u);

        float o0 = Mv[0], o1 = Mv[1], o2 = Mv[2], o3 = Mv[3];
        float pp0 = wv0 * o0;
        pp0 = fmaf(wv1, o1, pp0);
        float pp1 = wv2 * o2;
        pp1 = fmaf(wv3, o3, pp1);
        Mv[0] = fmaf(wv0, fmaf(-o0, e_c, a_c), o0);
        Mv[1] = fmaf(wv1, fmaf(-o1, e_c, a_c), o1);
        Mv[2] = fmaf(wv2, fmaf(-o2, e_c, a_c), o2);
        Mv[3] = fmaf(wv3, fmaf(-o3, e_c, a_c), o3);
        float part = pp0 + pp1;

        part += quad_swap1(part);
        part += quad_swap2(part);
        part += row_ror4(part);
        part += row_ror8(part);       // full 16-lane (64-m) sum
        if (p == 0) rp[(size_t)(t0 + u) * DIM] = part;
    }
}

__global__ __launch_bounds__(512) void kC(const float* __restrict__ Mv0,
                                          const u16* __restrict__ w_in,
                                          const u32* __restrict__ ea_in,
                                          float* __restrict__ rd) {
    __shared__ __align__(16) u16 wlds[2][32][64];    // 8 KB
    __shared__ __align__(16) u32 ealds[2][32][32];   // 8 KB
    const int tid = threadIdx.x;
    const int p = tid & 15;
    const int dl = tid >> 4;          // 0..31
    const int ds = blockIdx.x, b = blockIdx.y;
    const int d = ds * 32 + dl;
    const int m0 = p * 4;

    const char* wsrc  = (const char*)(w_in + (size_t)b * LL * MM);          // 64 KB/batch
    const char* easrc = (const char*)(ea_in + (size_t)b * LL * DIM + ds * 32);
    float* rp = rd + (size_t)b * LL * DIM + d;

    auto dma = [&](int c, int bufi) {
        if (tid < 256) {
            // w tile: 32 steps x 128 B, contiguous 4 KB
            const char* wt = wsrc + (size_t)c * 4096;
            ld16(wt + tid * 16, (char*)&wlds[bufi][0][0] + tid * 16);
        } else {
            // ea tile: 32 rows x 128 B (row stride DIM*4 B)
            const int idx = tid - 256;
            const int tl = idx >> 3, wi = (idx & 7) * 16;
            ld16(easrc + (size_t)(c * 32 + tl) * (DIM * 4) + wi,
                 (char*)&ealds[bufi][0][0] + idx * 16);
        }
    };

    dma(0, 0);

    float Mv[4];
    #pragma unroll
    for (int j = 0; j < 4; ++j)
        Mv[j] = Mv0[(m0 + j) * DIM + d];

    __builtin_amdgcn_s_waitcnt(0x0F70);   // vmcnt(0): tile-0 DMA + Mv loads done
    __syncthreads();

    int buf = 0;
    for (int c = 0; c < LL / 32; ++c) {
        if (c + 1 < LL / 32) dma(c + 1, buf ^ 1);
        scan32(&wlds[buf][0][0], &ealds[buf][0][0], m0, dl, p, c * 32, Mv, rp);
        if (c + 1 < LL / 32) {
            __builtin_amdgcn_s_waitcnt(0x8F70);   // vmcnt(32): DMA retired, stores may fly
            __syncthreads();
            buf ^= 1;
        }
    }
}

// ---------------------------------------------------------------------------
// Kernel D (MFMA, A=hi only): f = tanh([rd,k]@Wf+bf); p = sigmoid(f@Wp+bp).
// 64 rows/block; rd staged via f2bf (hi), Ek gathered pre-converted.
// ---------------------------------------------------------------------------
__global__ __launch_bounds__(256) void kD(const int* __restrict__ q,
                                          const u16* __restrict__ ekbf,
                                          const u16* __restrict__ wfT_hi, const u16* __restrict__ wfT_lo,
                                          const float* __restrict__ bfv,
                                          const float* __restrict__ Wp, const float* __restrict__ bp,
                                          const float* __restrict__ rd,
                                          float* __restrict__ out) {
    __shared__ __align__(16) u16 xhi[4][16][264];   // 33792 B (fbuf overlays exactly)
    __shared__ float sred[64][4];
    const int tid = threadIdx.x;
    const int base = blockIdx.x * 64;
    const int row_l = tid >> 2;
    const int rts = row_l >> 4, ms = row_l & 15;
    const int d0 = (tid & 3) * 32;
    const int row = base + row_l;

    {   // x[:, 0:128) = rd -> bf16 hi
        const float* src = rd + (size_t)row * DIM + d0;
        #pragma unroll
        for (int c8 = 0; c8 < 4; ++c8) {
            float4 f0 = *reinterpret_cast<const float4*>(src + c8 * 8);
            float4 f1 = *reinterpret_cast<const float4*>(src + c8 * 8 + 4);
            float xs[8] = {f0.x, f0.y, f0.z, f0.w, f1.x, f1.y, f1.z, f1.w};
            bfrag h;
            #pragma unroll
            for (int j = 0; j < 8; ++j) h[j] = (short)f2bf(xs[j]);
            *reinterpret_cast<bfrag*>(&xhi[rts][ms][d0 + c8 * 8]) = h;
        }
    }
    {   // x[:, 128:256) = ekbf[q[row]] (already bf16)
        const u16* src = ekbf + (size_t)q[row] * DIM + d0;
        #pragma unroll
        for (int c8 = 0; c8 < 4; ++c8)
            *reinterpret_cast<bfrag*>(&xhi[rts][ms][128 + d0 + c8 * 8]) =
                *reinterpret_cast<const bfrag*>(src + c8 * 8);
    }
    __syncthreads();

    const int lane = tid & 63;
    const int wv = tid >> 6;
    const int nloc = lane & 15;
    const int quad = lane >> 4;
    float* fbuf = reinterpret_cast<float*>(&xhi[0][0][0]);   // overlay after sync

    f32x4 acc[2][4];
    #pragma unroll
    for (int dt = 0; dt < 2; ++dt)
        #pragma unroll
        for (int t = 0; t < 4; ++t) acc[dt][t] = 0.f;

    #pragma unroll
    for (int dt = 0; dt < 2; ++dt) {
        const int n = (wv * 2 + dt) * 16 + nloc;
        bfrag Bh[8], Bl[8];
        #pragma unroll
        for (int kc = 0; kc < 8; ++kc) {
            const int ko = kc * 32 + quad * 8;
            Bh[kc] = *reinterpret_cast<const bfrag*>(wfT_hi + n * 256 + ko);
            Bl[kc] = *reinterpret_cast<const bfrag*>(wfT_lo + n * 256 + ko);
        }
        #pragma unroll
        for (int rt = 0; rt < 4; ++rt) {
            #pragma unroll
            for (int kc = 0; kc < 8; ++kc) {
                const int ko = kc * 32 + quad * 8;
                bfrag Ah = *reinterpret_cast<const bfrag*>(&xhi[rt][nloc][ko]);
                acc[dt][rt] = __builtin_amdgcn_mfma_f32_16x16x32_bf16(Ah, Bh[kc], acc[dt][rt], 0, 0, 0);
                acc[dt][rt] = __builtin_amdgcn_mfma_f32_16x16x32_bf16(Ah, Bl[kc], acc[dt][rt], 0, 0, 0);
            }
        }
    }
    __syncthreads();   // LDS x reads done before fbuf overlay

    #pragma unroll
    for (int dt = 0; dt < 2; ++dt) {
        const int n = (wv * 2 + dt) * 16 + nloc;
        const float bfn = bfv[n], wpn = Wp[n];
        #pragma unroll
        for (int rt = 0; rt < 4; ++rt)
            #pragma unroll
            for (int rg = 0; rg < 4; ++rg)
                fbuf[(rt * 16 + quad * 4 + rg) * 132 + n] = tanhf_fast(acc[dt][rt][rg] + bfn) * wpn;
    }
    __syncthreads();

    {
        float s = 0.f;
        const int c = tid & 3;
        #pragma unroll
        for (int k = 0; k < 32; ++k) s += fbuf[row_l * 132 + c * 32 + k];
        sred[row_l][c] = s;
    }
    __syncthreads();
    if (tid < 64)
        out[base + tid] = sigmoidf_fast(sred[tid][0] + sred[tid][1] + sred[tid][2] + sred[tid][3] + bp[0]);
}

// ---------------------------------------------------------------------------
extern "C" void kernel_launch(void* const* d_in, const int* in_sizes, int n_in,
                              void* d_out, int out_size, void* d_ws, size_t ws_size,
                              hipStream_t stream) {
    const int*   q   = (const int*)d_in[0];
    const int*   r   = (const int*)d_in[1];
    const float* Ek  = (const float*)d_in[2];
    const float* Ev  = (const float*)d_in[3];
    const float* Mk  = (const float*)d_in[4];
    const float* Mv0 = (const float*)d_in[5];
    const float* We  = (const float*)d_in[6];
    const float* be  = (const float*)d_in[7];
    const float* Wa  = (const float*)d_in[8];
    const float* ba  = (const float*)d_in[9];
    const float* Wf  = (const float*)d_in[10];
    const float* bfv = (const float*)d_in[11];
    const float* Wp  = (const float*)d_in[12];
    const float* bp  = (const float*)d_in[13];
    float* out = (float*)d_out;

    u16*  w_buf  = (u16*)d_ws;                                 // 4 MB
    u32*  ea_buf = (u32*)(w_buf + (size_t)NROWS * MM);         // 16 MB
    float* rd    = (float*)(ea_buf + (size_t)NROWS * DIM);     // 16 MB

    // prepped bf16 data right after rd (~1.1 MB)
    u16* weT_hi = (u16*)(rd + (size_t)NROWS * DIM);
    u16* weT_lo = weT_hi + 16384;
    u16* waT_hi = weT_lo + 16384;
    u16* waT_lo = waT_hi + 16384;
    u16* wfT_hi = waT_lo + 16384;
    u16* wfT_lo = wfT_hi + 32768;
    u16* mkT_hi = wfT_lo + 32768;
    u16* mkT_lo = mkT_hi + 8192;
    u16* ekbf   = mkT_lo + 8192;      // 128000 u16
    u16* evbf   = ekbf + 128000;      // 256000 u16

    kP<<<dim3(128), 256, 0, stream>>>(We, Wa, Wf, Mk, Ek, Ev,
                                      weT_hi, weT_lo, waT_hi, waT_lo,
                                      wfT_hi, wfT_lo, mkT_hi, mkT_lo, ekbf, evbf);
    kAB<<<dim3(1024), 256, 0, stream>>>(q, r, ekbf, evbf, mkT_hi, mkT_lo,
                                        weT_hi, weT_lo, waT_hi, waT_lo,
                                        be, ba, w_buf, ea_buf);
    kC<<<dim3(4, BB), 512, 0, stream>>>(Mv0, w_buf, ea_buf, rd);
    kD<<<dim3(NROWS / 64), 256, 0, stream>>>(q, ekbf, wfT_hi, wfT_lo, bfv, Wp, bp, rd, out);
}

// Round 6
// 177.941 us; speedup vs baseline: 1.1045x; 1.0034x over previous
//
#include <hip/hip_runtime.h>
#include <hip/hip_bf16.h>

#define NUM_C 1000
#define DIM   128
#define MM    64
#define BB    64
#define LL    512
#define NROWS (BB * LL)   // 32768

typedef unsigned short u16;
typedef unsigned int   u32;
typedef short bfrag __attribute__((ext_vector_type(8)));   // 8 bf16 (4 VGPRs)
typedef float f32x4 __attribute__((ext_vector_type(4)));   // MFMA acc

__device__ __forceinline__ float sigmoidf_fast(float x) { return 1.f / (1.f + __expf(-x)); }
__device__ __forceinline__ float tanhf_fast(float x) { return 1.f - 2.f / (__expf(2.f * x) + 1.f); }

__device__ __forceinline__ u16 f2bf(float x) {            // RNE f32->bf16 bits
    u32 u = __float_as_uint(x);
    return (u16)((u + 0x7FFFu + ((u >> 16) & 1u)) >> 16);
}
__device__ __forceinline__ float bf2f(u16 h) { return __uint_as_float(((u32)h) << 16); }

// DPP quad_perm swaps + row rotates (VALU-only, verified rounds 5-14)
__device__ __forceinline__ float quad_swap1(float x) {
    return __int_as_float(__builtin_amdgcn_mov_dpp(__float_as_int(x), 0xB1, 0xF, 0xF, true));
}
__device__ __forceinline__ float quad_swap2(float x) {
    return __int_as_float(__builtin_amdgcn_mov_dpp(__float_as_int(x), 0x4E, 0xF, 0xF, true));
}
__device__ __forceinline__ float row_ror4(float x) {
    return __int_as_float(__builtin_amdgcn_mov_dpp(__float_as_int(x), 0x124, 0xF, 0xF, true));
}
__device__ __forceinline__ float row_ror8(float x) {
    return __int_as_float(__builtin_amdgcn_mov_dpp(__float_as_int(x), 0x128, 0xF, 0xF, true));
}

// async global->LDS DMA, 16B per lane, LDS dest = wave-uniform base + lane*16
__device__ __forceinline__ void ld16(const void* g, void* l) {
    __builtin_amdgcn_global_load_lds(
        (const __attribute__((address_space(1))) unsigned int*)g,
        (__attribute__((address_space(3))) unsigned int*)l, 16, 0, 0);
}

// ---------------------------------------------------------------------------
// Prep: B-side weights as bf16 hi/lo ([n][k] transposed); A-side embeddings
// Ek/Ev pre-converted to bf16 hi ONCE (removes per-row conversion in kAB/kD).
// ---------------------------------------------------------------------------
__global__ __launch_bounds__(256) void kP(const float* __restrict__ We,
                                          const float* __restrict__ Wa,
                                          const float* __restrict__ Wf,
                                          const float* __restrict__ Mk,
                                          const float* __restrict__ Ek,
                                          const float* __restrict__ Ev,
                                          u16* weT_hi, u16* weT_lo,
                                          u16* waT_hi, u16* waT_lo,
                                          u16* wfT_hi, u16* wfT_lo,
                                          u16* mkT_hi, u16* mkT_lo,
                                          u16* ekbf, u16* evbf) {
    int idx = blockIdx.x * 256 + threadIdx.x;   // 0..32767
    if (idx < 128 * 128) {
        int n = idx >> 7, k = idx & 127;
        float we = We[k * DIM + n];
        u16 h = f2bf(we);
        weT_hi[idx] = h; weT_lo[idx] = f2bf(we - bf2f(h));
        float wa = Wa[k * DIM + n];
        u16 h2 = f2bf(wa);
        waT_hi[idx] = h2; waT_lo[idx] = f2bf(wa - bf2f(h2));
    }
    if (idx < 64 * 128) {
        float mk = Mk[idx];
        u16 h = f2bf(mk);
        mkT_hi[idx] = h; mkT_lo[idx] = f2bf(mk - bf2f(h));
    }
    {
        int n = idx >> 8, k = idx & 255;
        float wf = Wf[k * DIM + n];
        u16 h = f2bf(wf);
        wfT_hi[idx] = h; wfT_lo[idx] = f2bf(wf - bf2f(h));
    }
    for (int i = idx; i < NUM_C * DIM; i += 32768) ekbf[i] = f2bf(Ek[i]);
    for (int i = idx; i < 2 * NUM_C * DIM; i += 32768) evbf[i] = f2bf(Ev[i]);
}

// ---------------------------------------------------------------------------
// Fused kAB (MFMA, A=bf16-hi only, B=hi+lo). Blocks [0,512): kA role.
// Blocks [512,1024): kB role. 64 rows/block; staging = pure u16 gather.
// Outputs compressed: w as bf16 u16, (e,a) packed as u32 (2x bf16).
// ---------------------------------------------------------------------------
__global__ __launch_bounds__(256) void kAB(const int* __restrict__ q,
                                           const int* __restrict__ r,
                                           const u16* __restrict__ ekbf,
                                           const u16* __restrict__ evbf,
                                           const u16* __restrict__ mkT_hi, const u16* __restrict__ mkT_lo,
                                           const u16* __restrict__ weT_hi, const u16* __restrict__ weT_lo,
                                           const u16* __restrict__ waT_hi, const u16* __restrict__ waT_lo,
                                           const float* __restrict__ be, const float* __restrict__ ba,
                                           u16* __restrict__ w_out,
                                           u32* __restrict__ ea_out) {
    __shared__ __align__(16) u16 shi[4][16][136];
    __shared__ float slab[4][64];
    const int tid = threadIdx.x;
    const int lane = tid & 63;
    const int wv = tid >> 6;
    const int nloc = lane & 15;
    const int quad = lane >> 4;

    if (blockIdx.x < 512) {
        // ---------------- kA role ----------------
        const int base = blockIdx.x * 64;
        {   // stage k = ekbf[q] (already bf16)
            const int row_l = tid >> 2;
            const int rts = row_l >> 4, ms = row_l & 15;
            const int d0 = (tid & 3) * 32;
            const u16* src = ekbf + (size_t)q[base + row_l] * DIM + d0;
            #pragma unroll
            for (int c8 = 0; c8 < 4; ++c8)
                *reinterpret_cast<bfrag*>(&shi[rts][ms][d0 + c8 * 8]) =
                    *reinterpret_cast<const bfrag*>(src + c8 * 8);
        }
        __syncthreads();

        const int n = wv * 16 + nloc;      // m index
        bfrag Bh[4], Bl[4];
        #pragma unroll
        for (int kc = 0; kc < 4; ++kc) {
            const int ko = kc * 32 + quad * 8;
            Bh[kc] = *reinterpret_cast<const bfrag*>(mkT_hi + n * DIM + ko);
            Bl[kc] = *reinterpret_cast<const bfrag*>(mkT_lo + n * DIM + ko);
        }

        f32x4 acc[4];
        #pragma unroll
        for (int t = 0; t < 4; ++t) acc[t] = 0.f;

        #pragma unroll
        for (int rt = 0; rt < 4; ++rt) {
            #pragma unroll
            for (int kc = 0; kc < 4; ++kc) {
                const int ko = kc * 32 + quad * 8;
                bfrag Ah = *reinterpret_cast<const bfrag*>(&shi[rt][nloc][ko]);
                acc[rt] = __builtin_amdgcn_mfma_f32_16x16x32_bf16(Ah, Bh[kc], acc[rt], 0, 0, 0);
                acc[rt] = __builtin_amdgcn_mfma_f32_16x16x32_bf16(Ah, Bl[kc], acc[rt], 0, 0, 0);
            }
        }

        float ex[4][4];
        #pragma unroll
        for (int rt = 0; rt < 4; ++rt) {
            #pragma unroll
            for (int rg = 0; rg < 4; ++rg) {
                float e = __expf(acc[rt][rg]);
                ex[rt][rg] = e;
                float s = e;
                s += __shfl_xor(s, 1);
                s += __shfl_xor(s, 2);
                s += __shfl_xor(s, 4);
                s += __shfl_xor(s, 8);
                if (nloc == 0) slab[wv][rt * 16 + quad * 4 + rg] = s;
            }
        }
        __syncthreads();

        #pragma unroll
        for (int rt = 0; rt < 4; ++rt) {
            #pragma unroll
            for (int rg = 0; rg < 4; ++rg) {
                const int row = rt * 16 + quad * 4 + rg;
                float tot = slab[0][row] + slab[1][row] + slab[2][row] + slab[3][row];
                w_out[(size_t)(base + row) * MM + n] = f2bf(ex[rt][rg] / tot);
            }
        }
    } else {
        // ---------------- kB role ----------------
        const int base = (blockIdx.x - 512) * 64;
        {   // stage v = evbf[x] (already bf16)
            const int row_l = tid >> 2;
            const int rts = row_l >> 4, ms = row_l & 15;
            const int d0 = (tid & 3) * 32;
            const int row = base + row_l;
            const int x = q[row] + NUM_C * r[row];
            const u16* src = evbf + (size_t)x * DIM + d0;
            #pragma unroll
            for (int c8 = 0; c8 < 4; ++c8)
                *reinterpret_cast<bfrag*>(&shi[rts][ms][d0 + c8 * 8]) =
                    *reinterpret_cast<const bfrag*>(src + c8 * 8);
        }
        __syncthreads();

        #pragma unroll
        for (int dt = 0; dt < 2; ++dt) {
            const int n = (wv * 2 + dt) * 16 + nloc;
            bfrag Beh[4], Bel[4], Bah[4], Bal[4];
            #pragma unroll
            for (int kc = 0; kc < 4; ++kc) {
                const int ko = kc * 32 + quad * 8;
                Beh[kc] = *reinterpret_cast<const bfrag*>(weT_hi + n * DIM + ko);
                Bel[kc] = *reinterpret_cast<const bfrag*>(weT_lo + n * DIM + ko);
                Bah[kc] = *reinterpret_cast<const bfrag*>(waT_hi + n * DIM + ko);
                Bal[kc] = *reinterpret_cast<const bfrag*>(waT_lo + n * DIM + ko);
            }
            f32x4 acc_e[4], acc_a[4];
            #pragma unroll
            for (int t = 0; t < 4; ++t) { acc_e[t] = 0.f; acc_a[t] = 0.f; }

            #pragma unroll
            for (int rt = 0; rt < 4; ++rt) {
                #pragma unroll
                for (int kc = 0; kc < 4; ++kc) {
                    const int ko = kc * 32 + quad * 8;
                    bfrag Ah = *reinterpret_cast<const bfrag*>(&shi[rt][nloc][ko]);
                    acc_e[rt] = __builtin_amdgcn_mfma_f32_16x16x32_bf16(Ah, Beh[kc], acc_e[rt], 0, 0, 0);
                    acc_a[rt] = __builtin_amdgcn_mfma_f32_16x16x32_bf16(Ah, Bah[kc], acc_a[rt], 0, 0, 0);
                    acc_e[rt] = __builtin_amdgcn_mfma_f32_16x16x32_bf16(Ah, Bel[kc], acc_e[rt], 0, 0, 0);
                    acc_a[rt] = __builtin_amdgcn_mfma_f32_16x16x32_bf16(Ah, Bal[kc], acc_a[rt], 0, 0, 0);
                }
            }
            const float bev = be[n], bav = ba[n];
            #pragma unroll
            for (int rt = 0; rt < 4; ++rt) {
                #pragma unroll
                for (int rg = 0; rg < 4; ++rg) {
                    const int row = base + rt * 16 + quad * 4 + rg;
                    float ev = sigmoidf_fast(acc_e[rt][rg] + bev);
                    float av = tanhf_fast(acc_a[rt][rg] + bav);
                    ea_out[(size_t)row * DIM + n] = (u32)f2bf(ev) | ((u32)f2bf(av) << 16);
                }
            }
        }
    }
}

// ---------------------------------------------------------------------------
// Kernel C (r19): r18 compressed tiles + SOFTWARE-PIPELINED REDUCE.
// Model from r15-r18: time/step = VALU-issue / duty, duty ~0.5, the lost
// duty being the serial 4-stage DPP reduce chain (with DPP hazard waits)
// on every step's critical path. The reduce does NOT feed the recurrence
// (only Mv does, a 2-FMA chain), so it is pipelined across 4 steps: a
// rotating 4-slot register file; each iteration runs one stage of four
// DIFFERENT steps' reductions (s1@u-1, s2@u-2, s3@u-3, s4+store@u-4).
// Slot ops are ~8 instructions apart -> no DPP hazard stalls, no serial
// chain. Tile-end flush = 10 stage-ops + 4 stores (amortized ~0.4/step).
// rd is now stored as bf16 (identical rounding to kD's old staging ->
// bit-identical result), halving rd traffic and simplifying kD.
// ---------------------------------------------------------------------------
__device__ __forceinline__ void scan32(const u16* wb, const u32* eab,
                                       int m0, int dl, int p, int t0,
                                       float (&Mv)[4], u16* rp) {
    uint2 wq[4];
    u32   eq[4];
    #pragma unroll
    for (int u = 0; u < 4; ++u) {
        wq[u] = *reinterpret_cast<const uint2*>(wb + u * 64 + m0);
        eq[u] = eab[u * 32 + dl];
    }
    float pr[4];
    #pragma unroll
    for (int u = 0; u < 32; ++u) {
        uint2 wp = wq[u & 3];
        u32   ep = eq[u & 3];
        if (u + 4 < 32) {
            wq[u & 3] = *reinterpret_cast<const uint2*>(wb + (u + 4) * 64 + m0);
            eq[u & 3] = eab[(u + 4) * 32 + dl];
        }
        // stage 4 + store for step u-4 (resident in slot u&3, s3 applied last iter)
        if (u >= 4) {
            float f = pr[u & 3];
            f += row_ror8(f);
            if (p == 0) rp[(size_t)(t0 + u - 4) * DIM] = f2bf(f);
        }
        float wv0 = __uint_as_float(wp.x << 16);
        float wv1 = __uint_as_float(wp.x & 0xffff0000u);
        float wv2 = __uint_as_float(wp.y << 16);
        float wv3 = __uint_as_float(wp.y & 0xffff0000u);
        float e_c = __uint_as_float(ep << 16);
        float a_c = __uint_as_float(ep & 0xffff0000u);

        float o0 = Mv[0], o1 = Mv[1], o2 = Mv[2], o3 = Mv[3];
        float pp0 = wv0 * o0;
        pp0 = fmaf(wv1, o1, pp0);
        float pp1 = wv2 * o2;
        pp1 = fmaf(wv3, o3, pp1);
        Mv[0] = fmaf(wv0, fmaf(-o0, e_c, a_c), o0);
        Mv[1] = fmaf(wv1, fmaf(-o1, e_c, a_c), o1);
        Mv[2] = fmaf(wv2, fmaf(-o2, e_c, a_c), o2);
        Mv[3] = fmaf(wv3, fmaf(-o3, e_c, a_c), o3);
        pr[u & 3] = pp0 + pp1;   // fresh partial enters the pipeline

        if (u >= 1) { float f = pr[(u - 1) & 3]; pr[(u - 1) & 3] = f + quad_swap1(f); }
        if (u >= 2) { float f = pr[(u - 2) & 3]; pr[(u - 2) & 3] = f + quad_swap2(f); }
        if (u >= 3) { float f = pr[(u - 3) & 3]; pr[(u - 3) & 3] = f + row_ror4(f); }
    }
    // flush steps 28..31 (slots 0..3): remaining stages + store
    #pragma unroll
    for (int s = 28; s < 32; ++s) {
        float f = pr[s & 3];
        if (s >= 31) f += quad_swap1(f);   // step 31 lacks s1
        if (s >= 30) f += quad_swap2(f);   // steps 30,31 lack s2
        if (s >= 29) f += row_ror4(f);     // steps 29..31 lack s3
        f += row_ror8(f);
        if (p == 0) rp[(size_t)(t0 + s) * DIM] = f2bf(f);
    }
}

__global__ __launch_bounds__(512) void kC(const float* __restrict__ Mv0,
                                          const u16* __restrict__ w_in,
                                          const u32* __restrict__ ea_in,
                                          u16* __restrict__ rd) {
    __shared__ __align__(16) u16 wlds[2][32][64];    // 8 KB
    __shared__ __align__(16) u32 ealds[2][32][32];   // 8 KB
    const int tid = threadIdx.x;
    const int p = tid & 15;
    const int dl = tid >> 4;          // 0..31
    const int ds = blockIdx.x, b = blockIdx.y;
    const int d = ds * 32 + dl;
    const int m0 = p * 4;

    const char* wsrc  = (const char*)(w_in + (size_t)b * LL * MM);          // 64 KB/batch
    const char* easrc = (const char*)(ea_in + (size_t)b * LL * DIM + ds * 32);
    u16* rp = rd + (size_t)b * LL * DIM + d;

    auto dma = [&](int c, int bufi) {
        if (tid < 256) {
            // w tile: 32 steps x 128 B, contiguous 4 KB
            const char* wt = wsrc + (size_t)c * 4096;
            ld16(wt + tid * 16, (char*)&wlds[bufi][0][0] + tid * 16);
        } else {
            // ea tile: 32 rows x 128 B (row stride DIM*4 B)
            const int idx = tid - 256;
            const int tl = idx >> 3, wi = (idx & 7) * 16;
            ld16(easrc + (size_t)(c * 32 + tl) * (DIM * 4) + wi,
                 (char*)&ealds[bufi][0][0] + idx * 16);
        }
    };

    dma(0, 0);

    float Mv[4];
    #pragma unroll
    for (int j = 0; j < 4; ++j)
        Mv[j] = Mv0[(m0 + j) * DIM + d];

    __builtin_amdgcn_s_waitcnt(0x0F70);   // vmcnt(0): tile-0 DMA + Mv loads done
    __syncthreads();

    int buf = 0;
    for (int c = 0; c < LL / 32; ++c) {
        if (c + 1 < LL / 32) dma(c + 1, buf ^ 1);
        scan32(&wlds[buf][0][0], &ealds[buf][0][0], m0, dl, p, c * 32, Mv, rp);
        if (c + 1 < LL / 32) {
            __builtin_amdgcn_s_waitcnt(0x8F70);   // vmcnt(32): DMA retired, stores may fly
            __syncthreads();
            buf ^= 1;
        }
    }
}

// ---------------------------------------------------------------------------
// Kernel D (MFMA, A=hi only): f = tanh([rd,k]@Wf+bf); p = sigmoid(f@Wp+bp).
// 64 rows/block; rd arrives already bf16 (kC rounds identically to the old
// staging), so x staging is a pure u16 copy for both halves.
// ---------------------------------------------------------------------------
__global__ __launch_bounds__(256) void kD(const int* __restrict__ q,
                                          const u16* __restrict__ ekbf,
                                          const u16* __restrict__ wfT_hi, const u16* __restrict__ wfT_lo,
                                          const float* __restrict__ bfv,
                                          const float* __restrict__ Wp, const float* __restrict__ bp,
                                          const u16* __restrict__ rd,
                                          float* __restrict__ out) {
    __shared__ __align__(16) u16 xhi[4][16][264];   // 33792 B (fbuf overlays exactly)
    __shared__ float sred[64][4];
    const int tid = threadIdx.x;
    const int base = blockIdx.x * 64;
    const int row_l = tid >> 2;
    const int rts = row_l >> 4, ms = row_l & 15;
    const int d0 = (tid & 3) * 32;
    const int row = base + row_l;

    {   // x[:, 0:128) = rd (already bf16)
        const u16* src = rd + (size_t)row * DIM + d0;
        #pragma unroll
        for (int c8 = 0; c8 < 4; ++c8)
            *reinterpret_cast<bfrag*>(&xhi[rts][ms][d0 + c8 * 8]) =
                *reinterpret_cast<const bfrag*>(src + c8 * 8);
    }
    {   // x[:, 128:256) = ekbf[q[row]] (already bf16)
        const u16* src = ekbf + (size_t)q[row] * DIM + d0;
        #pragma unroll
        for (int c8 = 0; c8 < 4; ++c8)
            *reinterpret_cast<bfrag*>(&xhi[rts][ms][128 + d0 + c8 * 8]) =
                *reinterpret_cast<const bfrag*>(src + c8 * 8);
    }
    __syncthreads();

    const int lane = tid & 63;
    const int wv = tid >> 6;
    const int nloc = lane & 15;
    const int quad = lane >> 4;
    float* fbuf = reinterpret_cast<float*>(&xhi[0][0][0]);   // overlay after sync

    f32x4 acc[2][4];
    #pragma unroll
    for (int dt = 0; dt < 2; ++dt)
        #pragma unroll
        for (int t = 0; t < 4; ++t) acc[dt][t] = 0.f;

    #pragma unroll
    for (int dt = 0; dt < 2; ++dt) {
        const int n = (wv * 2 + dt) * 16 + nloc;
        bfrag Bh[8], Bl[8];
        #pragma unroll
        for (int kc = 0; kc < 8; ++kc) {
            const int ko = kc * 32 + quad * 8;
            Bh[kc] = *reinterpret_cast<const bfrag*>(wfT_hi + n * 256 + ko);
            Bl[kc] = *reinterpret_cast<const bfrag*>(wfT_lo + n * 256 + ko);
        }
        #pragma unroll
        for (int rt = 0; rt < 4; ++rt) {
            #pragma unroll
            for (int kc = 0; kc < 8; ++kc) {
                const int ko = kc * 32 + quad * 8;
                bfrag Ah = *reinterpret_cast<const bfrag*>(&xhi[rt][nloc][ko]);
                acc[dt][rt] = __builtin_amdgcn_mfma_f32_16x16x32_bf16(Ah, Bh[kc], acc[dt][rt], 0, 0, 0);
                acc[dt][rt] = __builtin_amdgcn_mfma_f32_16x16x32_bf16(Ah, Bl[kc], acc[dt][rt], 0, 0, 0);
            }
        }
    }
    __syncthreads();   // LDS x reads done before fbuf overlay

    #pragma unroll
    for (int dt = 0; dt < 2; ++dt) {
        const int n = (wv * 2 + dt) * 16 + nloc;
        const float bfn = bfv[n], wpn = Wp[n];
        #pragma unroll
        for (int rt = 0; rt < 4; ++rt)
            #pragma unroll
            for (int rg = 0; rg < 4; ++rg)
                fbuf[(rt * 16 + quad * 4 + rg) * 132 + n] = tanhf_fast(acc[dt][rt][rg] + bfn) * wpn;
    }
    __syncthreads();

    {
        float s = 0.f;
        const int c = tid & 3;
        #pragma unroll
        for (int k = 0; k < 32; ++k) s += fbuf[row_l * 132 + c * 32 + k];
        sred[row_l][c] = s;
    }
    __syncthreads();
    if (tid < 64)
        out[base + tid] = sigmoidf_fast(sred[tid][0] + sred[tid][1] + sred[tid][2] + sred[tid][3] + bp[0]);
}

// ---------------------------------------------------------------------------
extern "C" void kernel_launch(void* const* d_in, const int* in_sizes, int n_in,
                              void* d_out, int out_size, void* d_ws, size_t ws_size,
                              hipStream_t stream) {
    const int*   q   = (const int*)d_in[0];
    const int*   r   = (const int*)d_in[1];
    const float* Ek  = (const float*)d_in[2];
    const float* Ev  = (const float*)d_in[3];
    const float* Mk  = (const float*)d_in[4];
    const float* Mv0 = (const float*)d_in[5];
    const float* We  = (const float*)d_in[6];
    const float* be  = (const float*)d_in[7];
    const float* Wa  = (const float*)d_in[8];
    const float* ba  = (const float*)d_in[9];
    const float* Wf  = (const float*)d_in[10];
    const float* bfv = (const float*)d_in[11];
    const float* Wp  = (const float*)d_in[12];
    const float* bp  = (const float*)d_in[13];
    float* out = (float*)d_out;

    u16*  w_buf  = (u16*)d_ws;                                 // 4 MB
    u32*  ea_buf = (u32*)(w_buf + (size_t)NROWS * MM);         // 16 MB
    u16*  rdbf   = (u16*)(ea_buf + (size_t)NROWS * DIM);       // 8 MB

    // prepped bf16 data right after rdbf (~1.1 MB)
    u16* weT_hi = rdbf + (size_t)NROWS * DIM;
    u16* weT_lo = weT_hi + 16384;
    u16* waT_hi = weT_lo + 16384;
    u16* waT_lo = waT_hi + 16384;
    u16* wfT_hi = waT_lo + 16384;
    u16* wfT_lo = wfT_hi + 32768;
    u16* mkT_hi = wfT_lo + 32768;
    u16* mkT_lo = mkT_hi + 8192;
    u16* ekbf   = mkT_lo + 8192;      // 128000 u16
    u16* evbf   = ekbf + 128000;      // 256000 u16

    kP<<<dim3(128), 256, 0, stream>>>(We, Wa, Wf, Mk, Ek, Ev,
                                      weT_hi, weT_lo, waT_hi, waT_lo,
                                      wfT_hi, wfT_lo, mkT_hi, mkT_lo, ekbf, evbf);
    kAB<<<dim3(1024), 256, 0, stream>>>(q, r, ekbf, evbf, mkT_hi, mkT_lo,
                                        weT_hi, weT_lo, waT_hi, waT_lo,
                                        be, ba, w_buf, ea_buf);
    kC<<<dim3(4, BB), 512, 0, stream>>>(Mv0, w_buf, ea_buf, rdbf);
    kD<<<dim3(NROWS / 64), 256, 0, stream>>>(q, ekbf, wfT_hi, wfT_lo, bfv, Wp, bp, rdbf, out);
}

// Round 7
// 171.717 us; speedup vs baseline: 1.1446x; 1.0362x over previous
//
#include <hip/hip_runtime.h>
#include <hip/hip_bf16.h>

#define NUM_C 1000
#define DIM   128
#define MM    64
#define BB    64
#define LL    512
#define NROWS (BB * LL)   // 32768

typedef unsigned short u16;
typedef unsigned int   u32;
typedef short bfrag __attribute__((ext_vector_type(8)));   // 8 bf16 (4 VGPRs)
typedef float f32x4 __attribute__((ext_vector_type(4)));   // MFMA acc

__device__ __forceinline__ float sigmoidf_fast(float x) { return 1.f / (1.f + __expf(-x)); }
__device__ __forceinline__ float tanhf_fast(float x) { return 1.f - 2.f / (__expf(2.f * x) + 1.f); }

__device__ __forceinline__ u16 f2bf(float x) {            // RNE f32->bf16 bits
    u32 u = __float_as_uint(x);
    return (u16)((u + 0x7FFFu + ((u >> 16) & 1u)) >> 16);
}
__device__ __forceinline__ float bf2f(u16 h) { return __uint_as_float(((u32)h) << 16); }

// DPP quad_perm swaps + row rotates (VALU-only, verified rounds 5-14)
__device__ __forceinline__ float quad_swap1(float x) {
    return __int_as_float(__builtin_amdgcn_mov_dpp(__float_as_int(x), 0xB1, 0xF, 0xF, true));
}
__device__ __forceinline__ float quad_swap2(float x) {
    return __int_as_float(__builtin_amdgcn_mov_dpp(__float_as_int(x), 0x4E, 0xF, 0xF, true));
}
__device__ __forceinline__ float row_ror4(float x) {
    return __int_as_float(__builtin_amdgcn_mov_dpp(__float_as_int(x), 0x124, 0xF, 0xF, true));
}
__device__ __forceinline__ float row_ror8(float x) {
    return __int_as_float(__builtin_amdgcn_mov_dpp(__float_as_int(x), 0x128, 0xF, 0xF, true));
}

// async global->LDS DMA, 16B per lane, LDS dest = wave-uniform base + lane*16
__device__ __forceinline__ void ld16(const void* g, void* l) {
    __builtin_amdgcn_global_load_lds(
        (const __attribute__((address_space(1))) unsigned int*)g,
        (__attribute__((address_space(3))) unsigned int*)l, 16, 0, 0);
}

// ---------------------------------------------------------------------------
// Prep: B-side weights as bf16 hi/lo ([n][k] transposed); A-side embeddings
// Ek/Ev pre-converted to bf16 hi ONCE (removes per-row conversion in kAB/kD).
// ---------------------------------------------------------------------------
__global__ __launch_bounds__(256) void kP(const float* __restrict__ We,
                                          const float* __restrict__ Wa,
                                          const float* __restrict__ Wf,
                                          const float* __restrict__ Mk,
                                          const float* __restrict__ Ek,
                                          const float* __restrict__ Ev,
                                          u16* weT_hi, u16* weT_lo,
                                          u16* waT_hi, u16* waT_lo,
                                          u16* wfT_hi, u16* wfT_lo,
                                          u16* mkT_hi, u16* mkT_lo,
                                          u16* ekbf, u16* evbf) {
    int idx = blockIdx.x * 256 + threadIdx.x;   // 0..32767
    if (idx < 128 * 128) {
        int n = idx >> 7, k = idx & 127;
        float we = We[k * DIM + n];
        u16 h = f2bf(we);
        weT_hi[idx] = h; weT_lo[idx] = f2bf(we - bf2f(h));
        float wa = Wa[k * DIM + n];
        u16 h2 = f2bf(wa);
        waT_hi[idx] = h2; waT_lo[idx] = f2bf(wa - bf2f(h2));
    }
    if (idx < 64 * 128) {
        float mk = Mk[idx];
        u16 h = f2bf(mk);
        mkT_hi[idx] = h; mkT_lo[idx] = f2bf(mk - bf2f(h));
    }
    {
        int n = idx >> 8, k = idx & 255;
        float wf = Wf[k * DIM + n];
        u16 h = f2bf(wf);
        wfT_hi[idx] = h; wfT_lo[idx] = f2bf(wf - bf2f(h));
    }
    for (int i = idx; i < NUM_C * DIM; i += 32768) ekbf[i] = f2bf(Ek[i]);
    for (int i = idx; i < 2 * NUM_C * DIM; i += 32768) evbf[i] = f2bf(Ev[i]);
}

// ---------------------------------------------------------------------------
// Fused kAB (MFMA, A=bf16-hi only, B=hi+lo). Blocks [0,512): kA role.
// Blocks [512,1024): kB role. 64 rows/block; staging = pure u16 gather.
// Outputs f32 (r15 interface: w float, ea float2) -- bf16 compression (r18)
// measured NEUTRAL on kAB and +6 inst/step on kC; reverted.
// ---------------------------------------------------------------------------
__global__ __launch_bounds__(256) void kAB(const int* __restrict__ q,
                                           const int* __restrict__ r,
                                           const u16* __restrict__ ekbf,
                                           const u16* __restrict__ evbf,
                                           const u16* __restrict__ mkT_hi, const u16* __restrict__ mkT_lo,
                                           const u16* __restrict__ weT_hi, const u16* __restrict__ weT_lo,
                                           const u16* __restrict__ waT_hi, const u16* __restrict__ waT_lo,
                                           const float* __restrict__ be, const float* __restrict__ ba,
                                           float* __restrict__ w_out,
                                           float2* __restrict__ ea_out) {
    __shared__ __align__(16) u16 shi[4][16][136];
    __shared__ float slab[4][64];
    const int tid = threadIdx.x;
    const int lane = tid & 63;
    const int wv = tid >> 6;
    const int nloc = lane & 15;
    const int quad = lane >> 4;

    if (blockIdx.x < 512) {
        // ---------------- kA role ----------------
        const int base = blockIdx.x * 64;
        {   // stage k = ekbf[q] (already bf16)
            const int row_l = tid >> 2;
            const int rts = row_l >> 4, ms = row_l & 15;
            const int d0 = (tid & 3) * 32;
            const u16* src = ekbf + (size_t)q[base + row_l] * DIM + d0;
            #pragma unroll
            for (int c8 = 0; c8 < 4; ++c8)
                *reinterpret_cast<bfrag*>(&shi[rts][ms][d0 + c8 * 8]) =
                    *reinterpret_cast<const bfrag*>(src + c8 * 8);
        }
        __syncthreads();

        const int n = wv * 16 + nloc;      // m index
        bfrag Bh[4], Bl[4];
        #pragma unroll
        for (int kc = 0; kc < 4; ++kc) {
            const int ko = kc * 32 + quad * 8;
            Bh[kc] = *reinterpret_cast<const bfrag*>(mkT_hi + n * DIM + ko);
            Bl[kc] = *reinterpret_cast<const bfrag*>(mkT_lo + n * DIM + ko);
        }

        f32x4 acc[4];
        #pragma unroll
        for (int t = 0; t < 4; ++t) acc[t] = 0.f;

        #pragma unroll
        for (int rt = 0; rt < 4; ++rt) {
            #pragma unroll
            for (int kc = 0; kc < 4; ++kc) {
                const int ko = kc * 32 + quad * 8;
                bfrag Ah = *reinterpret_cast<const bfrag*>(&shi[rt][nloc][ko]);
                acc[rt] = __builtin_amdgcn_mfma_f32_16x16x32_bf16(Ah, Bh[kc], acc[rt], 0, 0, 0);
                acc[rt] = __builtin_amdgcn_mfma_f32_16x16x32_bf16(Ah, Bl[kc], acc[rt], 0, 0, 0);
            }
        }

        float ex[4][4];
        #pragma unroll
        for (int rt = 0; rt < 4; ++rt) {
            #pragma unroll
            for (int rg = 0; rg < 4; ++rg) {
                float e = __expf(acc[rt][rg]);
                ex[rt][rg] = e;
                float s = e;
                s += __shfl_xor(s, 1);
                s += __shfl_xor(s, 2);
                s += __shfl_xor(s, 4);
                s += __shfl_xor(s, 8);
                if (nloc == 0) slab[wv][rt * 16 + quad * 4 + rg] = s;
            }
        }
        __syncthreads();

        #pragma unroll
        for (int rt = 0; rt < 4; ++rt) {
            #pragma unroll
            for (int rg = 0; rg < 4; ++rg) {
                const int row = rt * 16 + quad * 4 + rg;
                float tot = slab[0][row] + slab[1][row] + slab[2][row] + slab[3][row];
                w_out[(size_t)(base + row) * MM + n] = ex[rt][rg] / tot;
            }
        }
    } else {
        // ---------------- kB role ----------------
        const int base = (blockIdx.x - 512) * 64;
        {   // stage v = evbf[x] (already bf16)
            const int row_l = tid >> 2;
            const int rts = row_l >> 4, ms = row_l & 15;
            const int d0 = (tid & 3) * 32;
            const int row = base + row_l;
            const int x = q[row] + NUM_C * r[row];
            const u16* src = evbf + (size_t)x * DIM + d0;
            #pragma unroll
            for (int c8 = 0; c8 < 4; ++c8)
                *reinterpret_cast<bfrag*>(&shi[rts][ms][d0 + c8 * 8]) =
                    *reinterpret_cast<const bfrag*>(src + c8 * 8);
        }
        __syncthreads();

        #pragma unroll
        for (int dt = 0; dt < 2; ++dt) {
            const int n = (wv * 2 + dt) * 16 + nloc;
            bfrag Beh[4], Bel[4], Bah[4], Bal[4];
            #pragma unroll
            for (int kc = 0; kc < 4; ++kc) {
                const int ko = kc * 32 + quad * 8;
                Beh[kc] = *reinterpret_cast<const bfrag*>(weT_hi + n * DIM + ko);
                Bel[kc] = *reinterpret_cast<const bfrag*>(weT_lo + n * DIM + ko);
                Bah[kc] = *reinterpret_cast<const bfrag*>(waT_hi + n * DIM + ko);
                Bal[kc] = *reinterpret_cast<const bfrag*>(waT_lo + n * DIM + ko);
            }
            f32x4 acc_e[4], acc_a[4];
            #pragma unroll
            for (int t = 0; t < 4; ++t) { acc_e[t] = 0.f; acc_a[t] = 0.f; }

            #pragma unroll
            for (int rt = 0; rt < 4; ++rt) {
                #pragma unroll
                for (int kc = 0; kc < 4; ++kc) {
                    const int ko = kc * 32 + quad * 8;
                    bfrag Ah = *reinterpret_cast<const bfrag*>(&shi[rt][nloc][ko]);
                    acc_e[rt] = __builtin_amdgcn_mfma_f32_16x16x32_bf16(Ah, Beh[kc], acc_e[rt], 0, 0, 0);
                    acc_a[rt] = __builtin_amdgcn_mfma_f32_16x16x32_bf16(Ah, Bah[kc], acc_a[rt], 0, 0, 0);
                    acc_e[rt] = __builtin_amdgcn_mfma_f32_16x16x32_bf16(Ah, Bel[kc], acc_e[rt], 0, 0, 0);
                    acc_a[rt] = __builtin_amdgcn_mfma_f32_16x16x32_bf16(Ah, Bal[kc], acc_a[rt], 0, 0, 0);
                }
            }
            const float bev = be[n], bav = ba[n];
            #pragma unroll
            for (int rt = 0; rt < 4; ++rt) {
                #pragma unroll
                for (int rg = 0; rg < 4; ++rg) {
                    const int row = base + rt * 16 + quad * 4 + rg;
                    float2 ea;
                    ea.x = sigmoidf_fast(acc_e[rt][rg] + bev);
                    ea.y = tanhf_fast(acc_a[rt][rg] + bav);
                    ea_out[(size_t)row * DIM + n] = ea;
                }
            }
        }
    }
}

// ---------------------------------------------------------------------------
// Kernel C (r20): r15's measured-best instruction stream (f32 tiles, b128 w +
// b64 ea reads, PF=4 rolling prefetch, serial DPP reduce, split pp chains,
// f32 rd store) with ONE isolated change: 256-thread blocks / 16 d each,
// grid (8, BB) = 512 blocks = 2 INDEPENDENT BARRIER DOMAINS per CU.
// Rationale (r15-r19 model): kC is VALU-issue-bound at ~50% duty; the lost
// duty is barrier/vmcnt drain + dependent-chain gaps at 2 waves/SIMD. A
// co-resident independent block fills those slots. Cost: w-tile DMA issued
// twice per CU (L2-absorbed, +2 wave-inst/tile) -- negligible.
// ---------------------------------------------------------------------------
__device__ __forceinline__ void scan32(const float* wb, const float2* eab,
                                       int m0, int dl, int p, int t0,
                                       float (&Mv)[4], float* rp) {
    float4 wq[4];
    float2 eq[4];
    #pragma unroll
    for (int u = 0; u < 4; ++u) {
        wq[u] = *reinterpret_cast<const float4*>(wb + u * 64 + m0);
        eq[u] = eab[u * 16 + dl];
    }
    #pragma unroll
    for (int u = 0; u < 32; ++u) {
        float4 w4 = wq[u & 3];
        float2 ea = eq[u & 3];
        if (u + 4 < 32) {
            wq[u & 3] = *reinterpret_cast<const float4*>(wb + (u + 4) * 64 + m0);
            eq[u & 3] = eab[(u + 4) * 16 + dl];
        }
        float wv0 = w4.x, wv1 = w4.y, wv2 = w4.z, wv3 = w4.w;
        float e_c = ea.x, a_c = ea.y;

        float o0 = Mv[0], o1 = Mv[1], o2 = Mv[2], o3 = Mv[3];
        float pp0 = wv0 * o0;
        pp0 = fmaf(wv1, o1, pp0);
        float pp1 = wv2 * o2;
        pp1 = fmaf(wv3, o3, pp1);
        Mv[0] = fmaf(wv0, fmaf(-o0, e_c, a_c), o0);
        Mv[1] = fmaf(wv1, fmaf(-o1, e_c, a_c), o1);
        Mv[2] = fmaf(wv2, fmaf(-o2, e_c, a_c), o2);
        Mv[3] = fmaf(wv3, fmaf(-o3, e_c, a_c), o3);
        float part = pp0 + pp1;

        part += quad_swap1(part);
        part += quad_swap2(part);
        part += row_ror4(part);
        part += row_ror8(part);       // full 16-lane (64-m) sum
        if (p == 0) rp[(size_t)(t0 + u) * DIM] = part;
    }
}

__global__ __launch_bounds__(256) void kC(const float* __restrict__ Mv0,
                                          const float* __restrict__ w_in,
                                          const float2* __restrict__ ea_in,
                                          float* __restrict__ rd) {
    __shared__ __align__(16) float  wlds[2][32][64];    // 16 KB
    __shared__ __align__(16) float2 ealds[2][32][16];   // 8 KB
    const int tid = threadIdx.x;
    const int p  = tid & 15;          // m-group 0..15
    const int dl = tid >> 4;          // d within slice 0..15
    const int ds = blockIdx.x;        // d-chunk 0..7
    const int b  = blockIdx.y;        // batch
    const int d  = ds * 16 + dl;
    const int m0 = p * 4;

    const char* wsrc  = (const char*)(w_in + (size_t)b * LL * MM);
    const char* easrc = (const char*)(ea_in + (size_t)b * LL * DIM + ds * 16);
    float* rp = rd + (size_t)b * LL * DIM + d;

    auto dma = [&](int c, int bufi) {
        const char* wt = wsrc + (size_t)c * 8192;         // w tile: 32x64 f32 = 8 KB
        char* wl = (char*)&wlds[bufi][0][0];
        const int off = tid * 16;                         // 0..4095
        ld16(wt + off, wl + off);
        ld16(wt + 4096 + off, wl + 4096 + off);
        // ea tile: 32 rows x 16 d x 8 B = 4 KB; 128 B per row, 8 lanes/row
        const int tl = tid >> 3, wi = (tid & 7) * 16;
        ld16(easrc + (size_t)(c * 32 + tl) * (DIM * 8) + wi,
             (char*)&ealds[bufi][0][0] + tid * 16);
    };

    dma(0, 0);

    float Mv[4];
    #pragma unroll
    for (int j = 0; j < 4; ++j)
        Mv[j] = Mv0[(m0 + j) * DIM + d];

    __builtin_amdgcn_s_waitcnt(0x0F70);   // vmcnt(0): tile-0 DMA + Mv loads done
    __syncthreads();

    int buf = 0;
    for (int c = 0; c < LL / 32; ++c) {
        if (c + 1 < LL / 32) dma(c + 1, buf ^ 1);
        scan32(&wlds[buf][0][0], &ealds[buf][0][0], m0, dl, p, c * 32, Mv, rp);
        if (c + 1 < LL / 32) {
            __builtin_amdgcn_s_waitcnt(0x8F70);   // vmcnt(32): DMAs retired, stores may fly
            __syncthreads();
            buf ^= 1;
        }
    }
}

// ---------------------------------------------------------------------------
// Kernel D (MFMA, A=hi only): f = tanh([rd,k]@Wf+bf); p = sigmoid(f@Wp+bp).
// 64 rows/block; rd staged via f2bf (hi), Ek gathered pre-converted.
// ---------------------------------------------------------------------------
__global__ __launch_bounds__(256) void kD(const int* __restrict__ q,
                                          const u16* __restrict__ ekbf,
                                          const u16* __restrict__ wfT_hi, const u16* __restrict__ wfT_lo,
                                          const float* __restrict__ bfv,
                                          const float* __restrict__ Wp, const float* __restrict__ bp,
                                          const float* __restrict__ rd,
                                          float* __restrict__ out) {
    __shared__ __align__(16) u16 xhi[4][16][264];   // 33792 B (fbuf overlays exactly)
    __shared__ float sred[64][4];
    const int tid = threadIdx.x;
    const int base = blockIdx.x * 64;
    const int row_l = tid >> 2;
    const int rts = row_l >> 4, ms = row_l & 15;
    const int d0 = (tid & 3) * 32;
    const int row = base + row_l;

    {   // x[:, 0:128) = rd -> bf16 hi
        const float* src = rd + (size_t)row * DIM + d0;
        #pragma unroll
        for (int c8 = 0; c8 < 4; ++c8) {
            float4 f0 = *reinterpret_cast<const float4*>(src + c8 * 8);
            float4 f1 = *reinterpret_cast<const float4*>(src + c8 * 8 + 4);
            float xs[8] = {f0.x, f0.y, f0.z, f0.w, f1.x, f1.y, f1.z, f1.w};
            bfrag h;
            #pragma unroll
            for (int j = 0; j < 8; ++j) h[j] = (short)f2bf(xs[j]);
            *reinterpret_cast<bfrag*>(&xhi[rts][ms][d0 + c8 * 8]) = h;
        }
    }
    {   // x[:, 128:256) = ekbf[q[row]] (already bf16)
        const u16* src = ekbf + (size_t)q[row] * DIM + d0;
        #pragma unroll
        for (int c8 = 0; c8 < 4; ++c8)
            *reinterpret_cast<bfrag*>(&xhi[rts][ms][128 + d0 + c8 * 8]) =
                *reinterpret_cast<const bfrag*>(src + c8 * 8);
    }
    __syncthreads();

    const int lane = tid & 63;
    const int wv = tid >> 6;
    const int nloc = lane & 15;
    const int quad = lane >> 4;
    float* fbuf = reinterpret_cast<float*>(&xhi[0][0][0]);   // overlay after sync

    f32x4 acc[2][4];
    #pragma unroll
    for (int dt = 0; dt < 2; ++dt)
        #pragma unroll
        for (int t = 0; t < 4; ++t) acc[dt][t] = 0.f;

    #pragma unroll
    for (int dt = 0; dt < 2; ++dt) {
        const int n = (wv * 2 + dt) * 16 + nloc;
        bfrag Bh[8], Bl[8];
        #pragma unroll
        for (int kc = 0; kc < 8; ++kc) {
            const int ko = kc * 32 + quad * 8;
            Bh[kc] = *reinterpret_cast<const bfrag*>(wfT_hi + n * 256 + ko);
            Bl[kc] = *reinterpret_cast<const bfrag*>(wfT_lo + n * 256 + ko);
        }
        #pragma unroll
        for (int rt = 0; rt < 4; ++rt) {
            #pragma unroll
            for (int kc = 0; kc < 8; ++kc) {
                const int ko = kc * 32 + quad * 8;
                bfrag Ah = *reinterpret_cast<const bfrag*>(&xhi[rt][nloc][ko]);
                acc[dt][rt] = __builtin_amdgcn_mfma_f32_16x16x32_bf16(Ah, Bh[kc], acc[dt][rt], 0, 0, 0);
                acc[dt][rt] = __builtin_amdgcn_mfma_f32_16x16x32_bf16(Ah, Bl[kc], acc[dt][rt], 0, 0, 0);
            }
        }
    }
    __syncthreads();   // LDS x reads done before fbuf overlay

    #pragma unroll
    for (int dt = 0; dt < 2; ++dt) {
        const int n = (wv * 2 + dt) * 16 + nloc;
        const float bfn = bfv[n], wpn = Wp[n];
        #pragma unroll
        for (int rt = 0; rt < 4; ++rt)
            #pragma unroll
            for (int rg = 0; rg < 4; ++rg)
                fbuf[(rt * 16 + quad * 4 + rg) * 132 + n] = tanhf_fast(acc[dt][rt][rg] + bfn) * wpn;
    }
    __syncthreads();

    {
        float s = 0.f;
        const int c = tid & 3;
        #pragma unroll
        for (int k = 0; k < 32; ++k) s += fbuf[row_l * 132 + c * 32 + k];
        sred[row_l][c] = s;
    }
    __syncthreads();
    if (tid < 64)
        out[base + tid] = sigmoidf_fast(sred[tid][0] + sred[tid][1] + sred[tid][2] + sred[tid][3] + bp[0]);
}

// ---------------------------------------------------------------------------
extern "C" void kernel_launch(void* const* d_in, const int* in_sizes, int n_in,
                              void* d_out, int out_size, void* d_ws, size_t ws_size,
                              hipStream_t stream) {
    const int*   q   = (const int*)d_in[0];
    const int*   r   = (const int*)d_in[1];
    const float* Ek  = (const float*)d_in[2];
    const float* Ev  = (const float*)d_in[3];
    const float* Mk  = (const float*)d_in[4];
    const float* Mv0 = (const float*)d_in[5];
    const float* We  = (const float*)d_in[6];
    const float* be  = (const float*)d_in[7];
    const float* Wa  = (const float*)d_in[8];
    const float* ba  = (const float*)d_in[9];
    const float* Wf  = (const float*)d_in[10];
    const float* bfv = (const float*)d_in[11];
    const float* Wp  = (const float*)d_in[12];
    const float* bp  = (const float*)d_in[13];
    float* out = (float*)d_out;

    float*  ws     = (float*)d_ws;
    float*  w_buf  = ws;                                      // 8 MB
    float2* ea_buf = (float2*)(w_buf + (size_t)NROWS * MM);   // 32 MB
    float*  rd     = (float*)(ea_buf + (size_t)NROWS * DIM);  // 16 MB

    // prepped bf16 data right after rd (~1.1 MB)
    u16* weT_hi = (u16*)(rd + (size_t)NROWS * DIM);
    u16* weT_lo = weT_hi + 16384;
    u16* waT_hi = weT_lo + 16384;
    u16* waT_lo = waT_hi + 16384;
    u16* wfT_hi = waT_lo + 16384;
    u16* wfT_lo = wfT_hi + 32768;
    u16* mkT_hi = wfT_lo + 32768;
    u16* mkT_lo = mkT_hi + 8192;
    u16* ekbf   = mkT_lo + 8192;      // 128000 u16
    u16* evbf   = ekbf + 128000;      // 256000 u16

    kP<<<dim3(128), 256, 0, stream>>>(We, Wa, Wf, Mk, Ek, Ev,
                                      weT_hi, weT_lo, waT_hi, waT_lo,
                                      wfT_hi, wfT_lo, mkT_hi, mkT_lo, ekbf, evbf);
    kAB<<<dim3(1024), 256, 0, stream>>>(q, r, ekbf, evbf, mkT_hi, mkT_lo,
                                        weT_hi, weT_lo, waT_hi, waT_lo,
                                        be, ba, w_buf, ea_buf);
    kC<<<dim3(8, BB), 256, 0, stream>>>(Mv0, w_buf, ea_buf, rd);
    kD<<<dim3(NROWS / 64), 256, 0, stream>>>(q, ekbf, wfT_hi, wfT_lo, bfv, Wp, bp, rd, out);
}